// Round 1
// baseline (718.994 us; speedup 1.0000x reference)
//
#include <hip/hip_runtime.h>
#include <math.h>

// ---------------------------------------------------------------------------
// BatchNorm statistics: column sums / sumsq via per-block partials + atomics
// ---------------------------------------------------------------------------
__global__ void bn_stats_kernel(const float* __restrict__ x, float* __restrict__ musum,
                                float* __restrict__ sqsum, int N, int F) {
  int t = threadIdx.x;  // F == blockDim.x == 256
  float s = 0.f, s2 = 0.f;
  for (int r = blockIdx.x; r < N; r += gridDim.x) {
    float v = x[(size_t)r * F + t];
    s += v;
    s2 += v * v;
  }
  atomicAdd(&musum[t], s);
  atomicAdd(&sqsum[t], s2);
}

__global__ void bn_finalize_kernel(const float* __restrict__ musum, const float* __restrict__ sqsum,
                                   const float* __restrict__ gamma, const float* __restrict__ beta,
                                   float* __restrict__ scale, float* __restrict__ shift, int N) {
  int t = threadIdx.x;
  float m = musum[t] / (float)N;
  float v = sqsum[t] / (float)N - m * m;
  float sc = gamma[t] * rsqrtf(v + 1e-5f);
  scale[t] = sc;
  shift[t] = beta[t] - m * sc;
}

__global__ void bn_apply_kernel(const float* __restrict__ x, const float* __restrict__ scale,
                                const float* __restrict__ shift, float* __restrict__ xin,
                                int total, int Fmask) {
  int i = blockIdx.x * blockDim.x + threadIdx.x;
  if (i < total) {
    int c = i & Fmask;
    xin[i] = x[i] * scale[c] + shift[c];
  }
}

// ---------------------------------------------------------------------------
// CSR build (indexed by dst). Edge e < E comes from edge_index, e >= E is a
// self loop (src = dst = e - E), matching the reference's concatenation order.
// ---------------------------------------------------------------------------
__global__ void csr_count_kernel(const int* __restrict__ ei, int E, int N, int* __restrict__ cnt) {
  int e = blockIdx.x * blockDim.x + threadIdx.x;
  int ET = E + N;
  if (e < ET) {
    int d = (e < E) ? ei[E + e] : (e - E);
    atomicAdd(&cnt[d], 1);
  }
}

__global__ void csr_scan_kernel(const int* __restrict__ cnt, int* __restrict__ row_ptr,
                                int* __restrict__ cursor, int N) {
  __shared__ int part[256];
  int t = threadIdx.x;
  int chunk = (N + 255) / 256;
  int lo = t * chunk;
  int hi = min(lo + chunk, N);
  int s = 0;
  for (int i = lo; i < hi; i++) s += cnt[i];
  part[t] = s;
  __syncthreads();
  // Hillis-Steele inclusive scan over 256 partials
  for (int off = 1; off < 256; off <<= 1) {
    int v = (t >= off) ? part[t - off] : 0;
    __syncthreads();
    part[t] += v;
    __syncthreads();
  }
  int run = (t == 0) ? 0 : part[t - 1];
  for (int i = lo; i < hi; i++) {
    row_ptr[i] = run;
    cursor[i] = run;
    run += cnt[i];
  }
  if (t == 255) row_ptr[N] = part[255];
}

__global__ void csr_fill_kernel(const int* __restrict__ ei, int E, int N,
                                int* __restrict__ cursor, int* __restrict__ csr_src) {
  int e = blockIdx.x * blockDim.x + threadIdx.x;
  int ET = E + N;
  if (e < ET) {
    int s, d;
    if (e < E) { s = ei[e]; d = ei[E + e]; }
    else       { s = e - E; d = s; }
    int pos = atomicAdd(&cursor[d], 1);
    csr_src[pos] = s;
  }
}

// ---------------------------------------------------------------------------
// fp32 tiled GEMM: C[M,Nc] = A[M,K] * B[K,Nc].
// A is given as two row-major segments (A1 with K1 cols, A2 with K-K1 cols) to
// implement concat([x_in, h1]) without materializing it. BK=16 divides both
// segment widths, so a K-tile never straddles the boundary.
// ---------------------------------------------------------------------------
__global__ __launch_bounds__(256) void gemm_kernel(
    const float* __restrict__ A1, const float* __restrict__ A2, int K1, int K,
    const float* __restrict__ B, float* __restrict__ Cout, int M, int Nc) {
  constexpr int BM = 64, BN = 64, BK = 16;
  __shared__ float As[BK][BM + 4];
  __shared__ float Bs[BK][BN];
  int t = threadIdx.x;
  int tx = t & 15, ty = t >> 4;
  int m0 = blockIdx.x * BM, n0 = blockIdx.y * BN;
  int K2 = K - K1;
  float acc[4][4] = {};
  for (int k0 = 0; k0 < K; k0 += BK) {
    // A tile: thread -> (row = t/4, kq = (t%4)*4), one float4 each
    {
      int row = t >> 2, kq = (t & 3) * 4;
      int m = m0 + row;
      int kk = k0 + kq;
      float4 a = make_float4(0.f, 0.f, 0.f, 0.f);
      if (m < M) {
        const float* src = (kk < K1) ? (A1 + (size_t)m * K1 + kk)
                                     : (A2 + (size_t)m * K2 + (kk - K1));
        a = *(const float4*)src;
      }
      As[kq + 0][row] = a.x;
      As[kq + 1][row] = a.y;
      As[kq + 2][row] = a.z;
      As[kq + 3][row] = a.w;
      // B tile: thread -> (k = t/16, nq = (t%16)*4)
      int kb = t >> 4, nq = (t & 15) * 4;
      float4 b = *(const float4*)(B + (size_t)(k0 + kb) * Nc + n0 + nq);
      *(float4*)&Bs[kb][nq] = b;
    }
    __syncthreads();
#pragma unroll
    for (int k = 0; k < BK; k++) {
      float4 a = *(const float4*)&As[k][ty * 4];
      float4 b = *(const float4*)&Bs[k][tx * 4];
      float av[4] = {a.x, a.y, a.z, a.w};
      float bv[4] = {b.x, b.y, b.z, b.w};
#pragma unroll
      for (int i = 0; i < 4; i++)
#pragma unroll
        for (int j = 0; j < 4; j++)
          acc[i][j] = fmaf(av[i], bv[j], acc[i][j]);
    }
    __syncthreads();
  }
#pragma unroll
  for (int i = 0; i < 4; i++) {
    int m = m0 + ty * 4 + i;
    if (m < M) {
      float4 v = make_float4(acc[i][0], acc[i][1], acc[i][2], acc[i][3]);
      *(float4*)(Cout + (size_t)m * Nc + n0 + tx * 4) = v;
    }
  }
}

// ---------------------------------------------------------------------------
// Attention logits: al_src[n,h] = <xw[n,h,:], a_src[h,:]>, same for a_dst.
// One 64-lane wave per (n,h) pair.
// ---------------------------------------------------------------------------
template <int H, int C>
__global__ void calc_al_kernel(const float* __restrict__ xw, const float* __restrict__ a_src,
                               const float* __restrict__ a_dst, float* __restrict__ alsrc,
                               float* __restrict__ aldst, int NH) {
  int wid = (blockIdx.x * blockDim.x + threadIdx.x) >> 6;
  int lane = threadIdx.x & 63;
  if (wid >= NH) return;
  int h = wid % H;
  float w1 = 0.f, w2 = 0.f;
  if (lane < C) {
    float v = xw[(size_t)wid * C + lane];
    w1 = v * a_src[h * C + lane];
    w2 = v * a_dst[h * C + lane];
  }
#pragma unroll
  for (int off = 32; off > 0; off >>= 1) {
    w1 += __shfl_down(w1, off);
    w2 += __shfl_down(w2, off);
  }
  if (lane == 0) {
    alsrc[wid] = w1;
    aldst[wid] = w2;
  }
}

// ---------------------------------------------------------------------------
// GAT aggregation, one block per destination node.
// Phase 1: per-head segment max + exp-sum (leaky_relu logits).
// Phase 2: chunked gather of xw[src] rows weighted by alpha.
// EPI=0: out[n, h*C+c] = prelu(acc + bias[h*C+c])          (concat layers)
// EPI=1: out[n, c]     = log_softmax(mean_h(acc) + bias[c]) (final layer)
// ---------------------------------------------------------------------------
template <int H, int C, int BLOCK, int CHUNK, int EPI>
__global__ __launch_bounds__(BLOCK) void gat_agg_kernel(
    const float* __restrict__ xw, const float* __restrict__ alsrc,
    const float* __restrict__ aldst, const int* __restrict__ row_ptr,
    const int* __restrict__ csr_src, const float* __restrict__ bias,
    const float* __restrict__ slope_p, float* __restrict__ out) {
  constexpr int HC = H * C;
  constexpr int PAIRS = (HC + BLOCK - 1) / BLOCK;
  constexpr int GH = BLOCK / H;

  int n = blockIdx.x;
  int t = threadIdx.x;

  __shared__ float s_aldst[H];
  __shared__ float s_m[H];
  __shared__ float s_s[H];
  __shared__ int s_srcbuf[CHUNK];
  __shared__ float s_w[CHUNK * H];
  __shared__ float s_red[BLOCK];

  if (t < H) s_aldst[t] = aldst[(size_t)n * H + t];
  int start = row_ptr[n];
  int deg = row_ptr[n + 1] - start;
  __syncthreads();

  int h = t % H;
  int g = t / H;
  float ad = s_aldst[h];

  // -- max over edges per head --
  float m = -1e30f;
  for (int j = g; j < deg; j += GH) {
    float e = alsrc[(size_t)csr_src[start + j] * H + h] + ad;
    e = (e >= 0.f) ? e : 0.2f * e;
    m = fmaxf(m, e);
  }
  s_red[t] = m;
  __syncthreads();
  for (int off = BLOCK / 2; off >= H; off >>= 1) {
    if (t < off) s_red[t] = fmaxf(s_red[t], s_red[t + off]);
    __syncthreads();
  }
  if (t < H) s_m[t] = s_red[t];
  __syncthreads();

  // -- sum of exp per head --
  float mh = s_m[h];
  float ssum = 0.f;
  for (int j = g; j < deg; j += GH) {
    float e = alsrc[(size_t)csr_src[start + j] * H + h] + ad;
    e = (e >= 0.f) ? e : 0.2f * e;
    ssum += __expf(e - mh);
  }
  s_red[t] = ssum;
  __syncthreads();
  for (int off = BLOCK / 2; off >= H; off >>= 1) {
    if (t < off) s_red[t] += s_red[t + off];
    __syncthreads();
  }
  if (t < H) s_s[t] = s_red[t];
  __syncthreads();

  // -- weighted gather --
  float acc[PAIRS];
#pragma unroll
  for (int p = 0; p < PAIRS; p++) acc[p] = 0.f;

  for (int cs = 0; cs < deg; cs += CHUNK) {
    int cn = min(CHUNK, deg - cs);
    __syncthreads();  // protect s_srcbuf / s_w reuse across chunks
    for (int i = t; i < cn; i += BLOCK) s_srcbuf[i] = csr_src[start + cs + i];
    __syncthreads();
    for (int idx = t; idx < cn * H; idx += BLOCK) {
      int j = idx / H, hh = idx % H;
      float e = alsrc[(size_t)s_srcbuf[j] * H + hh] + s_aldst[hh];
      e = (e >= 0.f) ? e : 0.2f * e;
      s_w[idx] = __expf(e - s_m[hh]) / (s_s[hh] + 1e-16f);
    }
    __syncthreads();
#pragma unroll
    for (int p = 0; p < PAIRS; p++) {
      int idx = t + p * BLOCK;
      if (HC % BLOCK == 0 || idx < HC) {
        int hh = idx / C;
        float a = acc[p];
        for (int j = 0; j < cn; j++)
          a = fmaf(s_w[j * H + hh], xw[(size_t)s_srcbuf[j] * HC + idx], a);
        acc[p] = a;
      }
    }
  }
  __syncthreads();

  if (EPI == 0) {
    float p = slope_p[0];
#pragma unroll
    for (int pp = 0; pp < PAIRS; pp++) {
      int idx = t + pp * BLOCK;
      if (HC % BLOCK == 0 || idx < HC) {
        float v = acc[pp] + bias[idx];
        out[(size_t)n * HC + idx] = (v >= 0.f) ? v : p * v;
      }
    }
  } else {
    __shared__ float s_acc[HC];
    __shared__ float s_vals[C];
    s_acc[t] = acc[0];
    __syncthreads();
    if (t < C) {
      float v = 0.f;
      for (int hh = 0; hh < H; hh++) v += s_acc[hh * C + t];
      s_vals[t] = v / (float)H + bias[t];
    }
    __syncthreads();
    if (t < C) {
      float mx = -1e30f;
      for (int c = 0; c < C; c++) mx = fmaxf(mx, s_vals[c]);
      float se = 0.f;
      for (int c = 0; c < C; c++) se += __expf(s_vals[c] - mx);
      out[(size_t)n * C + t] = s_vals[t] - mx - logf(se);
    }
  }
}

// ---------------------------------------------------------------------------
extern "C" void kernel_launch(void* const* d_in, const int* in_sizes, int n_in,
                              void* d_out, int out_size, void* d_ws, size_t ws_size,
                              hipStream_t stream) {
  const float* x        = (const float*)d_in[0];
  const int*   ei       = (const int*)d_in[1];
  const float* bn_gamma = (const float*)d_in[2];
  const float* bn_beta  = (const float*)d_in[3];
  const float* W1       = (const float*)d_in[4];
  const float* a1s      = (const float*)d_in[5];
  const float* a1d      = (const float*)d_in[6];
  const float* b1       = (const float*)d_in[7];
  const float* p1       = (const float*)d_in[8];
  const float* W2       = (const float*)d_in[9];
  const float* a2s      = (const float*)d_in[10];
  const float* a2d      = (const float*)d_in[11];
  const float* b2       = (const float*)d_in[12];
  const float* p2       = (const float*)d_in[13];
  const float* W3       = (const float*)d_in[14];
  const float* a3s      = (const float*)d_in[15];
  const float* a3d      = (const float*)d_in[16];
  const float* b3       = (const float*)d_in[17];
  float* out = (float*)d_out;

  const int F  = in_sizes[2];       // 256
  const int N  = in_sizes[0] / F;   // 20000
  const int E  = in_sizes[1] / 2;   // 320000
  const int ET = E + N;

  // ---- workspace bump allocator (256B aligned) ----
  size_t off = 0;
  auto alloc = [&](size_t bytes) -> char* {
    char* r = (char*)d_ws + off;
    off += (bytes + 255) & ~(size_t)255;
    return r;
  };
  float* musum  = (float*)alloc(F * 4);
  float* sqsum  = (float*)alloc(F * 4);
  float* scale  = (float*)alloc(F * 4);
  float* shift  = (float*)alloc(F * 4);
  int*   row_ptr = (int*)alloc((size_t)(N + 1) * 4);
  int*   cursor  = (int*)alloc((size_t)N * 4);
  int*   csr_src = (int*)alloc((size_t)ET * 4);
  float* al_s   = (float*)alloc((size_t)N * 16 * 4);
  float* al_d   = (float*)alloc((size_t)N * 16 * 4);
  float* x_in   = (float*)alloc((size_t)N * 256 * 4);
  float* xw1    = (float*)alloc((size_t)N * 1024 * 4);
  float* h1     = (float*)alloc((size_t)N * 1024 * 4);
  // layer 2/3 buffers alias the (dead after agg1) xw1 region
  float* xw2 = xw1;                  // N*64
  float* h2  = xw1 + (size_t)N * 64; // N*64
  float* xw3 = xw1 + (size_t)N * 128; // N*128

  // ---- BatchNorm ----
  hipMemsetAsync(musum, 0, (size_t)2 * F * 4, stream);  // musum+sqsum contiguous (F*4 is 256B-mult)
  bn_stats_kernel<<<256, 256, 0, stream>>>(x, musum, sqsum, N, F);
  bn_finalize_kernel<<<1, F, 0, stream>>>(musum, sqsum, bn_gamma, bn_beta, scale, shift, N);
  int totalXF = N * F;
  bn_apply_kernel<<<(totalXF + 255) / 256, 256, 0, stream>>>(x, scale, shift, x_in, totalXF, F - 1);

  // ---- CSR by dst ----
  hipMemsetAsync(cursor, 0, (size_t)N * 4, stream);
  csr_count_kernel<<<(ET + 255) / 256, 256, 0, stream>>>(ei, E, N, cursor);
  csr_scan_kernel<<<1, 256, 0, stream>>>(cursor, row_ptr, cursor, N);
  csr_fill_kernel<<<(ET + 255) / 256, 256, 0, stream>>>(ei, E, N, cursor, csr_src);

  // ---- Layer 1: [N,256] @ [256,1024], H=16, C=64, concat + PReLU ----
  {
    dim3 grid((N + 63) / 64, 1024 / 64);
    gemm_kernel<<<grid, 256, 0, stream>>>(x_in, x_in, 256, 256, W1, xw1, N, 1024);
    int NH = N * 16;
    calc_al_kernel<16, 64><<<(NH + 3) / 4, 256, 0, stream>>>(xw1, a1s, a1d, al_s, al_d, NH);
    gat_agg_kernel<16, 64, 256, 64, 0><<<N, 256, 0, stream>>>(
        xw1, al_s, al_d, row_ptr, csr_src, b1, p1, h1);
  }

  // ---- Layer 2: concat([x_in,h1]) [N,1280] @ [1280,64], H=8, C=8 ----
  {
    dim3 grid((N + 63) / 64, 64 / 64);
    gemm_kernel<<<grid, 256, 0, stream>>>(x_in, h1, 256, 1280, W2, xw2, N, 64);
    int NH = N * 8;
    calc_al_kernel<8, 8><<<(NH + 3) / 4, 256, 0, stream>>>(xw2, a2s, a2d, al_s, al_d, NH);
    gat_agg_kernel<8, 8, 64, 64, 0><<<N, 64, 0, stream>>>(
        xw2, al_s, al_d, row_ptr, csr_src, b2, p2, h2);
  }

  // ---- Layer 3: [N,64] @ [64,128], H=8, C=16, mean + log_softmax ----
  {
    dim3 grid((N + 63) / 64, 128 / 64);
    gemm_kernel<<<grid, 256, 0, stream>>>(h2, h2, 64, 64, W3, xw3, N, 128);
    int NH = N * 8;
    calc_al_kernel<8, 16><<<(NH + 3) / 4, 256, 0, stream>>>(xw3, a3s, a3d, al_s, al_d, NH);
    gat_agg_kernel<8, 16, 128, 64, 1><<<N, 128, 0, stream>>>(
        xw3, al_s, al_d, row_ptr, csr_src, b3, nullptr, out);
  }
}

// Round 2
// 473.410 us; speedup vs baseline: 1.5188x; 1.5188x over previous
//
#include <hip/hip_runtime.h>
#include <math.h>

typedef unsigned int u32;
typedef unsigned short u16;
typedef u32 u32x4 __attribute__((ext_vector_type(4)));
typedef float f32x4 __attribute__((ext_vector_type(4)));

__device__ __forceinline__ u16 f2bf(float f) {
  u32 u = __builtin_bit_cast(u32, f);
  return (u16)((u + 0x7FFFu + ((u >> 16) & 1u)) >> 16);
}
__device__ __forceinline__ float bf2f(u32 lo16) {
  return __builtin_bit_cast(float, lo16 << 16);
}
__device__ __forceinline__ void mfma16(f32x4& c, const u32x4& a, const u32x4& b) {
  asm volatile("v_mfma_f32_16x16x32_bf16 %0, %1, %2, %0" : "+v"(c) : "v"(a), "v"(b));
}

// ---------------------------------------------------------------------------
// BatchNorm
// ---------------------------------------------------------------------------
__global__ void bn_stats_kernel(const float* __restrict__ x, float* __restrict__ musum,
                                float* __restrict__ sqsum, int N, int F) {
  int t = threadIdx.x;  // F == 256
  float s = 0.f, s2 = 0.f;
  for (int r = blockIdx.x; r < N; r += gridDim.x) {
    float v = x[(size_t)r * F + t];
    s += v;
    s2 += v * v;
  }
  atomicAdd(&musum[t], s);
  atomicAdd(&sqsum[t], s2);
}

__global__ void bn_finalize_kernel(const float* __restrict__ musum, const float* __restrict__ sqsum,
                                   const float* __restrict__ gamma, const float* __restrict__ beta,
                                   float* __restrict__ scale, float* __restrict__ shift, int N) {
  int t = threadIdx.x;
  float m = musum[t] / (float)N;
  float v = sqsum[t] / (float)N - m * m;
  float sc = gamma[t] * rsqrtf(v + 1e-5f);
  scale[t] = sc;
  shift[t] = beta[t] - m * sc;
}

// writes bf16 x_in (only consumer is bf16 MFMA GEMMs)
__global__ void bn_apply_bf16_kernel(const float* __restrict__ x, const float* __restrict__ scale,
                                     const float* __restrict__ shift, u16* __restrict__ xin,
                                     int total, int Fmask) {
  int i = blockIdx.x * blockDim.x + threadIdx.x;
  if (i < total) {
    int c = i & Fmask;
    xin[i] = f2bf(x[i] * scale[c] + shift[c]);
  }
}

// ---------------------------------------------------------------------------
// CSR build (dst-indexed)
// ---------------------------------------------------------------------------
__global__ void csr_count_kernel(const int* __restrict__ ei, int E, int N, int* __restrict__ cnt) {
  int e = blockIdx.x * blockDim.x + threadIdx.x;
  int ET = E + N;
  if (e < ET) {
    int d = (e < E) ? ei[E + e] : (e - E);
    atomicAdd(&cnt[d], 1);
  }
}

__global__ void csr_scan_kernel(const int* __restrict__ cnt, int* __restrict__ row_ptr,
                                int* __restrict__ cursor, int N) {
  __shared__ int part[256];
  int t = threadIdx.x;
  int chunk = (N + 255) / 256;
  int lo = t * chunk;
  int hi = min(lo + chunk, N);
  int s = 0;
  for (int i = lo; i < hi; i++) s += cnt[i];
  part[t] = s;
  __syncthreads();
  for (int off = 1; off < 256; off <<= 1) {
    int v = (t >= off) ? part[t - off] : 0;
    __syncthreads();
    part[t] += v;
    __syncthreads();
  }
  int run = (t == 0) ? 0 : part[t - 1];
  for (int i = lo; i < hi; i++) {
    row_ptr[i] = run;
    cursor[i] = run;
    run += cnt[i];
  }
  if (t == 255) row_ptr[N] = part[255];
}

__global__ void csr_fill_kernel(const int* __restrict__ ei, int E, int N,
                                int* __restrict__ cursor, int* __restrict__ csr_src) {
  int e = blockIdx.x * blockDim.x + threadIdx.x;
  int ET = E + N;
  if (e < ET) {
    int s, d;
    if (e < E) { s = ei[e]; d = ei[E + e]; }
    else       { s = e - E; d = s; }
    int pos = atomicAdd(&cursor[d], 1);
    csr_src[pos] = s;
  }
}

// ---------------------------------------------------------------------------
// Pre-fragment weights: W fp32 [K][Nc] row-major -> Wt bf16 [Nc][K/8][8]
// (flattened: Wt[n*K + k]); makes GEMM B-tile staging a contiguous copy.
// ---------------------------------------------------------------------------
__global__ void wt_build_kernel(const float* __restrict__ W, u16* __restrict__ Wt, int K, int Nc) {
  int idx = blockIdx.x * blockDim.x + threadIdx.x;
  if (idx < K * Nc) {
    int n = idx / K, k = idx % K;
    Wt[idx] = f2bf(W[(size_t)k * Nc + n]);
  }
}

// ---------------------------------------------------------------------------
// bf16 MFMA GEMM: C[M,Nc] = A[M,K] * W[K,Nc], A given as two bf16 row-major
// segments (K1 | K-K1), W pre-fragmented as Wt [Nc][K/8][8] bf16.
// 256 threads = 4 waves in 2x2; wave tile (FM*16) x (FN*16); BK=32.
// LDS layouts As[m][kb][8], Bs[n][kb][8] are fragment-native: lane l reads
// chunk (row*4 + l/16) as one ds_read_b128.
// Writes Cf (fp32) and optionally Ch (bf16 copy).
// ---------------------------------------------------------------------------
template <int BM, int BN, int FM, int FN, bool WH>
__global__ __launch_bounds__(256) void mfma_gemm_kernel(
    const u16* __restrict__ A1, const u16* __restrict__ A2, int K1, int K,
    const u16* __restrict__ Wt, float* __restrict__ Cf, u16* __restrict__ Ch,
    int M, int Nc) {
  constexpr int BK = 32;
  constexpr int CA = (BM * BK) / (256 * 8);
  constexpr int CB = (BN * BK) / (256 * 8);
  static_assert(BM == 2 * FM * 16 && BN == 2 * FN * 16, "wave grid 2x2");
  __shared__ u16 As[BM * BK];
  __shared__ u16 Bs[BN * BK];
  int t = threadIdx.x;
  int m0 = blockIdx.x * BM, n0 = blockIdx.y * BN;
  int r = t & 15;
  int g = (t >> 4) & 3;  // lane/16
  int wid = t >> 6;
  int wm0 = (wid >> 1) * (FM * 16);
  int wn0 = (wid & 1) * (FN * 16);
  int K8 = K >> 3;
  int K2 = K - K1;

  f32x4 acc[FM][FN] = {};
  asm volatile("s_nop 7\n\ts_nop 7" :::);  // VALU acc-init -> MFMA SrcC hazard guard

  for (int k0 = 0; k0 < K; k0 += BK) {
    const u16* Aseg;
    int sA, kl;
    if (k0 < K1) { Aseg = A1; sA = K1; kl = k0; }
    else         { Aseg = A2; sA = K2; kl = k0 - K1; }
    __syncthreads();
#pragma unroll
    for (int i = 0; i < CA; i++) {
      int c = i * 256 + t;
      int m = c >> 2, kb = c & 3;
      *(u32x4*)(As + c * 8) =
          *(const u32x4*)(Aseg + (size_t)(m0 + m) * sA + kl + kb * 8);
    }
#pragma unroll
    for (int i = 0; i < CB; i++) {
      int c = i * 256 + t;
      int nn = c >> 2, kb = c & 3;
      *(u32x4*)(Bs + c * 8) =
          *(const u32x4*)(Wt + ((size_t)(n0 + nn) * K8 + (k0 >> 3) + kb) * 8);
    }
    __syncthreads();
    u32x4 af[FM], bfr[FN];
#pragma unroll
    for (int fi = 0; fi < FM; fi++)
      af[fi] = *(const u32x4*)(As + ((wm0 + fi * 16 + r) * 4 + g) * 8);
#pragma unroll
    for (int fj = 0; fj < FN; fj++)
      bfr[fj] = *(const u32x4*)(Bs + ((wn0 + fj * 16 + r) * 4 + g) * 8);
#pragma unroll
    for (int fi = 0; fi < FM; fi++)
#pragma unroll
      for (int fj = 0; fj < FN; fj++) mfma16(acc[fi][fj], af[fi], bfr[fj]);
  }
  asm volatile("s_nop 7\n\ts_nop 7" :::);  // MFMA -> VALU read hazard guard

#pragma unroll
  for (int fi = 0; fi < FM; fi++) {
#pragma unroll
    for (int fj = 0; fj < FN; fj++) {
#pragma unroll
      for (int v = 0; v < 4; v++) {
        int m = m0 + wm0 + fi * 16 + g * 4 + v;  // C/D: row=4*(lane>>4)+reg
        int nn = n0 + wn0 + fj * 16 + r;         //      col=lane&15
        if (m < M) {
          float val = acc[fi][fj][v];
          Cf[(size_t)m * Nc + nn] = val;
          if (WH) Ch[(size_t)m * Nc + nn] = f2bf(val);
        }
      }
    }
  }
}

// ---------------------------------------------------------------------------
// fp32 tiled GEMM (kept for tiny layer-3 GEMM)
// ---------------------------------------------------------------------------
__global__ __launch_bounds__(256) void gemm_kernel(
    const float* __restrict__ A1, const float* __restrict__ A2, int K1, int K,
    const float* __restrict__ B, float* __restrict__ Cout, int M, int Nc) {
  constexpr int BM = 64, BN = 64, BK = 16;
  __shared__ float As[BK][BM + 4];
  __shared__ float Bs[BK][BN];
  int t = threadIdx.x;
  int tx = t & 15, ty = t >> 4;
  int m0 = blockIdx.x * BM, n0 = blockIdx.y * BN;
  int K2 = K - K1;
  float acc[4][4] = {};
  for (int k0 = 0; k0 < K; k0 += BK) {
    {
      int row = t >> 2, kq = (t & 3) * 4;
      int m = m0 + row;
      int kk = k0 + kq;
      float4 a = make_float4(0.f, 0.f, 0.f, 0.f);
      if (m < M) {
        const float* src = (kk < K1) ? (A1 + (size_t)m * K1 + kk)
                                     : (A2 + (size_t)m * K2 + (kk - K1));
        a = *(const float4*)src;
      }
      As[kq + 0][row] = a.x;
      As[kq + 1][row] = a.y;
      As[kq + 2][row] = a.z;
      As[kq + 3][row] = a.w;
      int kb = t >> 4, nq = (t & 15) * 4;
      float4 b = *(const float4*)(B + (size_t)(k0 + kb) * Nc + n0 + nq);
      *(float4*)&Bs[kb][nq] = b;
    }
    __syncthreads();
#pragma unroll
    for (int k = 0; k < BK; k++) {
      float4 a = *(const float4*)&As[k][ty * 4];
      float4 b = *(const float4*)&Bs[k][tx * 4];
      float av[4] = {a.x, a.y, a.z, a.w};
      float bv[4] = {b.x, b.y, b.z, b.w};
#pragma unroll
      for (int i = 0; i < 4; i++)
#pragma unroll
        for (int j = 0; j < 4; j++)
          acc[i][j] = fmaf(av[i], bv[j], acc[i][j]);
    }
    __syncthreads();
  }
#pragma unroll
  for (int i = 0; i < 4; i++) {
    int m = m0 + ty * 4 + i;
    if (m < M) {
      float4 v = make_float4(acc[i][0], acc[i][1], acc[i][2], acc[i][3]);
      *(float4*)(Cout + (size_t)m * Nc + n0 + tx * 4) = v;
    }
  }
}

// ---------------------------------------------------------------------------
// Attention logits (fp32 xw)
// ---------------------------------------------------------------------------
template <int H, int C>
__global__ void calc_al_kernel(const float* __restrict__ xw, const float* __restrict__ a_src,
                               const float* __restrict__ a_dst, float* __restrict__ alsrc,
                               float* __restrict__ aldst, int NH) {
  int wid = (blockIdx.x * blockDim.x + threadIdx.x) >> 6;
  int lane = threadIdx.x & 63;
  if (wid >= NH) return;
  int h = wid % H;
  float w1 = 0.f, w2 = 0.f;
  if (lane < C) {
    float v = xw[(size_t)wid * C + lane];
    w1 = v * a_src[h * C + lane];
    w2 = v * a_dst[h * C + lane];
  }
#pragma unroll
  for (int off = 32; off > 0; off >>= 1) {
    w1 += __shfl_down(w1, off);
    w2 += __shfl_down(w2, off);
  }
  if (lane == 0) {
    alsrc[wid] = w1;
    aldst[wid] = w2;
  }
}

// ---------------------------------------------------------------------------
// Layer-1 aggregation: H=16, C=64, bf16 gather rows, bf16 h1 output.
// ---------------------------------------------------------------------------
__global__ __launch_bounds__(256) void gat_agg1_kernel(
    const u16* __restrict__ xwh, const float* __restrict__ alsrc,
    const float* __restrict__ aldst, const int* __restrict__ row_ptr,
    const int* __restrict__ csr_src, const float* __restrict__ bias,
    const float* __restrict__ slope_p, u16* __restrict__ out) {
  constexpr int H = 16, HC = 1024, BLOCK = 256, CHUNK = 64, GH = BLOCK / H;
  int n = blockIdx.x, t = threadIdx.x;
  __shared__ float s_aldst[H], s_m[H], s_r[H];
  __shared__ int s_srcbuf[CHUNK];
  __shared__ float s_w[CHUNK * H];
  __shared__ float s_red[BLOCK];

  if (t < H) s_aldst[t] = aldst[(size_t)n * H + t];
  int start = row_ptr[n];
  int deg = row_ptr[n + 1] - start;
  __syncthreads();

  int h = t & 15, g = t >> 4;
  float ad = s_aldst[h];
  float m = -1e30f;
  for (int j = g; j < deg; j += GH) {
    float e = alsrc[(size_t)csr_src[start + j] * H + h] + ad;
    e = (e >= 0.f) ? e : 0.2f * e;
    m = fmaxf(m, e);
  }
  s_red[t] = m;
  __syncthreads();
  for (int off = BLOCK / 2; off >= H; off >>= 1) {
    if (t < off) s_red[t] = fmaxf(s_red[t], s_red[t + off]);
    __syncthreads();
  }
  if (t < H) s_m[t] = s_red[t];
  __syncthreads();
  float mh = s_m[h], ss = 0.f;
  for (int j = g; j < deg; j += GH) {
    float e = alsrc[(size_t)csr_src[start + j] * H + h] + ad;
    e = (e >= 0.f) ? e : 0.2f * e;
    ss += __expf(e - mh);
  }
  s_red[t] = ss;
  __syncthreads();
  for (int off = BLOCK / 2; off >= H; off >>= 1) {
    if (t < off) s_red[t] += s_red[t + off];
    __syncthreads();
  }
  if (t < H) s_r[t] = 1.f / (s_red[t] + 1e-16f);
  __syncthreads();

  float a0 = 0.f, a1 = 0.f, a2 = 0.f, a3 = 0.f;
  int h0 = t >> 5, h1i = h0 + 8;  // heads of uint cols t and t+256
  for (int cs = 0; cs < deg; cs += CHUNK) {
    int cn = min(CHUNK, deg - cs);
    __syncthreads();
    for (int i = t; i < cn; i += BLOCK) s_srcbuf[i] = csr_src[start + cs + i];
    __syncthreads();
    for (int idx = t; idx < cn * H; idx += BLOCK) {
      int j = idx >> 4, hh = idx & 15;
      float e = alsrc[(size_t)s_srcbuf[j] * H + hh] + s_aldst[hh];
      e = (e >= 0.f) ? e : 0.2f * e;
      s_w[idx] = __expf(e - s_m[hh]) * s_r[hh];
    }
    __syncthreads();
    for (int j = 0; j < cn; j++) {
      const u32* rp = (const u32*)(xwh + (size_t)s_srcbuf[j] * HC);
      u32 v0 = rp[t], v1 = rp[t + 256];
      float w0 = s_w[(j << 4) + h0], w1 = s_w[(j << 4) + h1i];
      a0 = fmaf(w0, bf2f(v0 & 0xffffu), a0);
      a1 = fmaf(w0, bf2f(v0 >> 16), a1);
      a2 = fmaf(w1, bf2f(v1 & 0xffffu), a2);
      a3 = fmaf(w1, bf2f(v1 >> 16), a3);
    }
  }
  __syncthreads();

  float p = slope_p[0];
  int c0 = 2 * t, c1 = 512 + 2 * t;
  float v0 = a0 + bias[c0], v1 = a1 + bias[c0 + 1];
  float v2 = a2 + bias[c1], v3 = a3 + bias[c1 + 1];
  v0 = (v0 >= 0.f) ? v0 : p * v0;
  v1 = (v1 >= 0.f) ? v1 : p * v1;
  v2 = (v2 >= 0.f) ? v2 : p * v2;
  v3 = (v3 >= 0.f) ? v3 : p * v3;
  u32* op = (u32*)(out + (size_t)n * HC);
  op[t] = (u32)f2bf(v0) | ((u32)f2bf(v1) << 16);
  op[t + 256] = (u32)f2bf(v2) | ((u32)f2bf(v3) << 16);
}

// ---------------------------------------------------------------------------
// Generic fp32 aggregation (layers 2,3) — unchanged from R0.
// ---------------------------------------------------------------------------
template <int H, int C, int BLOCK, int CHUNK, int EPI>
__global__ __launch_bounds__(BLOCK) void gat_agg_kernel(
    const float* __restrict__ xw, const float* __restrict__ alsrc,
    const float* __restrict__ aldst, const int* __restrict__ row_ptr,
    const int* __restrict__ csr_src, const float* __restrict__ bias,
    const float* __restrict__ slope_p, float* __restrict__ out) {
  constexpr int HC = H * C;
  constexpr int PAIRS = (HC + BLOCK - 1) / BLOCK;
  constexpr int GH = BLOCK / H;

  int n = blockIdx.x;
  int t = threadIdx.x;

  __shared__ float s_aldst[H];
  __shared__ float s_m[H];
  __shared__ float s_s[H];
  __shared__ int s_srcbuf[CHUNK];
  __shared__ float s_w[CHUNK * H];
  __shared__ float s_red[BLOCK];

  if (t < H) s_aldst[t] = aldst[(size_t)n * H + t];
  int start = row_ptr[n];
  int deg = row_ptr[n + 1] - start;
  __syncthreads();

  int h = t % H;
  int g = t / H;
  float ad = s_aldst[h];

  float m = -1e30f;
  for (int j = g; j < deg; j += GH) {
    float e = alsrc[(size_t)csr_src[start + j] * H + h] + ad;
    e = (e >= 0.f) ? e : 0.2f * e;
    m = fmaxf(m, e);
  }
  s_red[t] = m;
  __syncthreads();
  for (int off = BLOCK / 2; off >= H; off >>= 1) {
    if (t < off) s_red[t] = fmaxf(s_red[t], s_red[t + off]);
    __syncthreads();
  }
  if (t < H) s_m[t] = s_red[t];
  __syncthreads();

  float mh = s_m[h];
  float ssum = 0.f;
  for (int j = g; j < deg; j += GH) {
    float e = alsrc[(size_t)csr_src[start + j] * H + h] + ad;
    e = (e >= 0.f) ? e : 0.2f * e;
    ssum += __expf(e - mh);
  }
  s_red[t] = ssum;
  __syncthreads();
  for (int off = BLOCK / 2; off >= H; off >>= 1) {
    if (t < off) s_red[t] += s_red[t + off];
    __syncthreads();
  }
  if (t < H) s_s[t] = 1.f / (s_red[t] + 1e-16f);
  __syncthreads();

  float acc[PAIRS];
#pragma unroll
  for (int p = 0; p < PAIRS; p++) acc[p] = 0.f;

  for (int cs = 0; cs < deg; cs += CHUNK) {
    int cn = min(CHUNK, deg - cs);
    __syncthreads();
    for (int i = t; i < cn; i += BLOCK) s_srcbuf[i] = csr_src[start + cs + i];
    __syncthreads();
    for (int idx = t; idx < cn * H; idx += BLOCK) {
      int j = idx / H, hh = idx % H;
      float e = alsrc[(size_t)s_srcbuf[j] * H + hh] + s_aldst[hh];
      e = (e >= 0.f) ? e : 0.2f * e;
      s_w[idx] = __expf(e - s_m[hh]) * s_s[hh];
    }
    __syncthreads();
#pragma unroll
    for (int p = 0; p < PAIRS; p++) {
      int idx = t + p * BLOCK;
      if (HC % BLOCK == 0 || idx < HC) {
        int hh = idx / C;
        float a = acc[p];
        for (int j = 0; j < cn; j++)
          a = fmaf(s_w[j * H + hh], xw[(size_t)s_srcbuf[j] * HC + idx], a);
        acc[p] = a;
      }
    }
  }
  __syncthreads();

  if (EPI == 0) {
    float p = slope_p[0];
#pragma unroll
    for (int pp = 0; pp < PAIRS; pp++) {
      int idx = t + pp * BLOCK;
      if (HC % BLOCK == 0 || idx < HC) {
        float v = acc[pp] + bias[idx];
        out[(size_t)n * HC + idx] = (v >= 0.f) ? v : p * v;
      }
    }
  } else {
    __shared__ float s_acc[HC];
    __shared__ float s_vals[C];
    s_acc[t] = acc[0];
    __syncthreads();
    if (t < C) {
      float v = 0.f;
      for (int hh = 0; hh < H; hh++) v += s_acc[hh * C + t];
      s_vals[t] = v / (float)H + bias[t];
    }
    __syncthreads();
    if (t < C) {
      float mx = -1e30f;
      for (int c = 0; c < C; c++) mx = fmaxf(mx, s_vals[c]);
      float se = 0.f;
      for (int c = 0; c < C; c++) se += __expf(s_vals[c] - mx);
      out[(size_t)n * C + t] = s_vals[t] - mx - logf(se);
    }
  }
}

// ---------------------------------------------------------------------------
extern "C" void kernel_launch(void* const* d_in, const int* in_sizes, int n_in,
                              void* d_out, int out_size, void* d_ws, size_t ws_size,
                              hipStream_t stream) {
  const float* x        = (const float*)d_in[0];
  const int*   ei       = (const int*)d_in[1];
  const float* bn_gamma = (const float*)d_in[2];
  const float* bn_beta  = (const float*)d_in[3];
  const float* W1       = (const float*)d_in[4];
  const float* a1s      = (const float*)d_in[5];
  const float* a1d      = (const float*)d_in[6];
  const float* b1       = (const float*)d_in[7];
  const float* p1       = (const float*)d_in[8];
  const float* W2       = (const float*)d_in[9];
  const float* a2s      = (const float*)d_in[10];
  const float* a2d      = (const float*)d_in[11];
  const float* b2       = (const float*)d_in[12];
  const float* p2       = (const float*)d_in[13];
  const float* W3       = (const float*)d_in[14];
  const float* a3s      = (const float*)d_in[15];
  const float* a3d      = (const float*)d_in[16];
  const float* b3       = (const float*)d_in[17];
  float* out = (float*)d_out;

  const int F  = in_sizes[2];       // 256
  const int N  = in_sizes[0] / F;   // 20000
  const int E  = in_sizes[1] / 2;   // 320000
  const int ET = E + N;
  const int MP = ((N + 127) / 128) * 128;  // 20096, MFMA row padding

  size_t off = 0;
  auto alloc = [&](size_t bytes) -> char* {
    char* r = (char*)d_ws + off;
    off += (bytes + 255) & ~(size_t)255;
    return r;
  };
  float* musum   = (float*)alloc(F * 4);
  float* sqsum   = (float*)alloc(F * 4);
  float* scale   = (float*)alloc(F * 4);
  float* shift   = (float*)alloc(F * 4);
  int*   row_ptr = (int*)alloc((size_t)(N + 1) * 4);
  int*   cursor  = (int*)alloc((size_t)N * 4);
  int*   csr_src = (int*)alloc((size_t)ET * 4);
  float* al_s    = (float*)alloc((size_t)N * 16 * 4);
  float* al_d    = (float*)alloc((size_t)N * 16 * 4);
  u16*   Wt1     = (u16*)alloc((size_t)256 * 1024 * 2);
  u16*   Wt2     = (u16*)alloc((size_t)1280 * 64 * 2);
  u16*   x_in_h  = (u16*)alloc((size_t)MP * 256 * 2);
  u16*   xw1h    = (u16*)alloc((size_t)MP * 1024 * 2);
  u16*   h1      = (u16*)alloc((size_t)MP * 1024 * 2);
  float* xw1f    = (float*)alloc((size_t)MP * 1024 * 4);
  // layer-2/3 fp32 buffers alias xw1f (dead after calc_al1)
  float* xw2 = xw1f;                     // MP*64
  float* h2  = xw1f + (size_t)MP * 64;   // N*64
  float* xw3 = xw1f + (size_t)MP * 128;  // N*128

  // ---- BatchNorm ----
  hipMemsetAsync(musum, 0, (size_t)2 * F * 4, stream);
  bn_stats_kernel<<<256, 256, 0, stream>>>(x, musum, sqsum, N, F);
  bn_finalize_kernel<<<1, F, 0, stream>>>(musum, sqsum, bn_gamma, bn_beta, scale, shift, N);
  int totalXF = N * F;
  bn_apply_bf16_kernel<<<(totalXF + 255) / 256, 256, 0, stream>>>(x, scale, shift, x_in_h,
                                                                  totalXF, F - 1);

  // ---- CSR by dst ----
  hipMemsetAsync(cursor, 0, (size_t)N * 4, stream);
  csr_count_kernel<<<(ET + 255) / 256, 256, 0, stream>>>(ei, E, N, cursor);
  csr_scan_kernel<<<1, 256, 0, stream>>>(cursor, row_ptr, cursor, N);
  csr_fill_kernel<<<(ET + 255) / 256, 256, 0, stream>>>(ei, E, N, cursor, csr_src);

  // ---- weight pre-fragmentation ----
  wt_build_kernel<<<(256 * 1024 + 255) / 256, 256, 0, stream>>>(W1, Wt1, 256, 1024);
  wt_build_kernel<<<(1280 * 64 + 255) / 256, 256, 0, stream>>>(W2, Wt2, 1280, 64);

  // ---- Layer 1: [N,256]@[256,1024] MFMA, H=16, C=64 ----
  {
    dim3 grid(MP / 128, 1024 / 128);
    mfma_gemm_kernel<128, 128, 4, 4, true><<<grid, 256, 0, stream>>>(
        x_in_h, x_in_h, 256, 256, Wt1, xw1f, xw1h, N, 1024);
    int NH = N * 16;
    calc_al_kernel<16, 64><<<(NH + 3) / 4, 256, 0, stream>>>(xw1f, a1s, a1d, al_s, al_d, NH);
    gat_agg1_kernel<<<N, 256, 0, stream>>>(xw1h, al_s, al_d, row_ptr, csr_src, b1, p1, h1);
  }

  // ---- Layer 2: concat([x_in,h1]) [N,1280]@[1280,64] MFMA, H=8, C=8 ----
  {
    dim3 grid((N + 63) / 64, 1);
    mfma_gemm_kernel<64, 64, 2, 2, false><<<grid, 256, 0, stream>>>(
        x_in_h, h1, 256, 1280, Wt2, xw2, nullptr, N, 64);
    int NH = N * 8;
    calc_al_kernel<8, 8><<<(NH + 3) / 4, 256, 0, stream>>>(xw2, a2s, a2d, al_s, al_d, NH);
    gat_agg_kernel<8, 8, 64, 64, 0><<<N, 64, 0, stream>>>(
        xw2, al_s, al_d, row_ptr, csr_src, b2, p2, h2);
  }

  // ---- Layer 3: [N,64]@[64,128] fp32, H=8, C=16, mean + log_softmax ----
  {
    dim3 grid((N + 63) / 64, 128 / 64);
    gemm_kernel<<<grid, 256, 0, stream>>>(h2, h2, 64, 64, W3, xw3, N, 128);
    int NH = N * 8;
    calc_al_kernel<8, 16><<<(NH + 3) / 4, 256, 0, stream>>>(xw3, a3s, a3d, al_s, al_d, NH);
    gat_agg_kernel<8, 16, 128, 64, 1><<<N, 128, 0, stream>>>(
        xw3, al_s, al_d, row_ptr, csr_src, b3, nullptr, out);
  }
}

// Round 3
// 398.437 us; speedup vs baseline: 1.8045x; 1.1882x over previous
//
#include <hip/hip_runtime.h>
#include <math.h>

typedef unsigned int u32;
typedef unsigned short u16;
typedef u32 u32x4 __attribute__((ext_vector_type(4)));
typedef float f32x4 __attribute__((ext_vector_type(4)));

__device__ __forceinline__ u16 f2bf(float f) {
  u32 u = __builtin_bit_cast(u32, f);
  return (u16)((u + 0x7FFFu + ((u >> 16) & 1u)) >> 16);
}
__device__ __forceinline__ float bf2f(u32 lo16) {
  return __builtin_bit_cast(float, lo16 << 16);
}
__device__ __forceinline__ void mfma16(f32x4& c, const u32x4& a, const u32x4& b) {
  asm volatile("v_mfma_f32_16x16x32_bf16 %0, %1, %2, %0" : "+v"(c) : "v"(a), "v"(b));
}
__device__ __forceinline__ float lrelu(float e) { return (e >= 0.f) ? e : 0.2f * e; }

// ---------------------------------------------------------------------------
// BatchNorm
// ---------------------------------------------------------------------------
__global__ void bn_stats_kernel(const float* __restrict__ x, float* __restrict__ musum,
                                float* __restrict__ sqsum, int N, int F) {
  int t = threadIdx.x;  // F == 256
  float s = 0.f, s2 = 0.f;
  for (int r = blockIdx.x; r < N; r += gridDim.x) {
    float v = x[(size_t)r * F + t];
    s += v;
    s2 += v * v;
  }
  atomicAdd(&musum[t], s);
  atomicAdd(&sqsum[t], s2);
}

__global__ void bn_finalize_kernel(const float* __restrict__ musum, const float* __restrict__ sqsum,
                                   const float* __restrict__ gamma, const float* __restrict__ beta,
                                   float* __restrict__ scale, float* __restrict__ shift, int N) {
  int t = threadIdx.x;
  float m = musum[t] / (float)N;
  float v = sqsum[t] / (float)N - m * m;
  float sc = gamma[t] * rsqrtf(v + 1e-5f);
  scale[t] = sc;
  shift[t] = beta[t] - m * sc;
}

__global__ void bn_apply_bf16_kernel(const float* __restrict__ x, const float* __restrict__ scale,
                                     const float* __restrict__ shift, u16* __restrict__ xin,
                                     int total, int Fmask) {
  int i = blockIdx.x * blockDim.x + threadIdx.x;
  if (i < total) {
    int c = i & Fmask;
    xin[i] = f2bf(x[i] * scale[c] + shift[c]);
  }
}

// ---------------------------------------------------------------------------
// CSR build (dst-indexed)
// ---------------------------------------------------------------------------
__global__ void csr_count_kernel(const int* __restrict__ ei, int E, int N, int* __restrict__ cnt) {
  int e = blockIdx.x * blockDim.x + threadIdx.x;
  int ET = E + N;
  if (e < ET) {
    int d = (e < E) ? ei[E + e] : (e - E);
    atomicAdd(&cnt[d], 1);
  }
}

__global__ void csr_scan_kernel(const int* __restrict__ cnt, int* __restrict__ row_ptr,
                                int* __restrict__ cursor, int N) {
  __shared__ int part[256];
  int t = threadIdx.x;
  int chunk = (N + 255) / 256;
  int lo = t * chunk;
  int hi = min(lo + chunk, N);
  int s = 0;
  for (int i = lo; i < hi; i++) s += cnt[i];
  part[t] = s;
  __syncthreads();
  for (int off = 1; off < 256; off <<= 1) {
    int v = (t >= off) ? part[t - off] : 0;
    __syncthreads();
    part[t] += v;
    __syncthreads();
  }
  int run = (t == 0) ? 0 : part[t - 1];
  for (int i = lo; i < hi; i++) {
    row_ptr[i] = run;
    cursor[i] = run;
    run += cnt[i];
  }
  if (t == 255) row_ptr[N] = part[255];
}

__global__ void csr_fill_kernel(const int* __restrict__ ei, int E, int N,
                                int* __restrict__ cursor, int* __restrict__ csr_src) {
  int e = blockIdx.x * blockDim.x + threadIdx.x;
  int ET = E + N;
  if (e < ET) {
    int s, d;
    if (e < E) { s = ei[e]; d = ei[E + e]; }
    else       { s = e - E; d = s; }
    int pos = atomicAdd(&cursor[d], 1);
    csr_src[pos] = s;
  }
}

// ---------------------------------------------------------------------------
// W fp32 [K][Nc] row-major -> Wt bf16 [Nc][K] (fragment-native for MFMA B)
// ---------------------------------------------------------------------------
__global__ void wt_build_kernel(const float* __restrict__ W, u16* __restrict__ Wt, int K, int Nc) {
  int idx = blockIdx.x * blockDim.x + threadIdx.x;
  if (idx < K * Nc) {
    int n = idx / K, k = idx % K;
    Wt[idx] = f2bf(W[(size_t)k * Nc + n]);
  }
}

// ---------------------------------------------------------------------------
// bf16 MFMA GEMM (see R1 comments). WF: write fp32 C, WH: write bf16 C.
// ---------------------------------------------------------------------------
template <int BM, int BN, int FM, int FN, bool WF, bool WH>
__global__ __launch_bounds__(256) void mfma_gemm_kernel(
    const u16* __restrict__ A1, const u16* __restrict__ A2, int K1, int K,
    const u16* __restrict__ Wt, float* __restrict__ Cf, u16* __restrict__ Ch,
    int M, int Nc) {
  constexpr int BK = 32;
  constexpr int CA = (BM * BK) / (256 * 8);
  constexpr int CB = (BN * BK) / (256 * 8);
  static_assert(BM == 2 * FM * 16 && BN == 2 * FN * 16, "wave grid 2x2");
  __shared__ u16 As[BM * BK];
  __shared__ u16 Bs[BN * BK];
  int t = threadIdx.x;
  int m0 = blockIdx.x * BM, n0 = blockIdx.y * BN;
  int r = t & 15;
  int g = (t >> 4) & 3;
  int wid = t >> 6;
  int wm0 = (wid >> 1) * (FM * 16);
  int wn0 = (wid & 1) * (FN * 16);
  int K8 = K >> 3;
  int K2 = K - K1;

  f32x4 acc[FM][FN] = {};
  asm volatile("s_nop 7\n\ts_nop 7" :::);  // VALU acc-init -> MFMA SrcC hazard guard

  for (int k0 = 0; k0 < K; k0 += BK) {
    const u16* Aseg;
    int sA, kl;
    if (k0 < K1) { Aseg = A1; sA = K1; kl = k0; }
    else         { Aseg = A2; sA = K2; kl = k0 - K1; }
    __syncthreads();
#pragma unroll
    for (int i = 0; i < CA; i++) {
      int c = i * 256 + t;
      int m = c >> 2, kb = c & 3;
      *(u32x4*)(As + c * 8) =
          *(const u32x4*)(Aseg + (size_t)(m0 + m) * sA + kl + kb * 8);
    }
#pragma unroll
    for (int i = 0; i < CB; i++) {
      int c = i * 256 + t;
      int nn = c >> 2, kb = c & 3;
      *(u32x4*)(Bs + c * 8) =
          *(const u32x4*)(Wt + ((size_t)(n0 + nn) * K8 + (k0 >> 3) + kb) * 8);
    }
    __syncthreads();
    u32x4 af[FM], bfr[FN];
#pragma unroll
    for (int fi = 0; fi < FM; fi++)
      af[fi] = *(const u32x4*)(As + ((wm0 + fi * 16 + r) * 4 + g) * 8);
#pragma unroll
    for (int fj = 0; fj < FN; fj++)
      bfr[fj] = *(const u32x4*)(Bs + ((wn0 + fj * 16 + r) * 4 + g) * 8);
#pragma unroll
    for (int fi = 0; fi < FM; fi++)
#pragma unroll
      for (int fj = 0; fj < FN; fj++) mfma16(acc[fi][fj], af[fi], bfr[fj]);
  }
  asm volatile("s_nop 7\n\ts_nop 7" :::);  // MFMA -> VALU read hazard guard

#pragma unroll
  for (int fi = 0; fi < FM; fi++) {
#pragma unroll
    for (int fj = 0; fj < FN; fj++) {
#pragma unroll
      for (int v = 0; v < 4; v++) {
        int m = m0 + wm0 + fi * 16 + g * 4 + v;
        int nn = n0 + wn0 + fj * 16 + r;
        if (m < M) {
          float val = acc[fi][fj][v];
          if (WF) Cf[(size_t)m * Nc + nn] = val;
          if (WH) Ch[(size_t)m * Nc + nn] = f2bf(val);
        }
      }
    }
  }
}

// ---------------------------------------------------------------------------
// fp32 tiled GEMM (tiny layer-3 GEMM)
// ---------------------------------------------------------------------------
__global__ __launch_bounds__(256) void gemm_kernel(
    const float* __restrict__ A1, const float* __restrict__ A2, int K1, int K,
    const float* __restrict__ B, float* __restrict__ Cout, int M, int Nc) {
  constexpr int BM = 64, BN = 64, BK = 16;
  __shared__ float As[BK][BM + 4];
  __shared__ float Bs[BK][BN];
  int t = threadIdx.x;
  int tx = t & 15, ty = t >> 4;
  int m0 = blockIdx.x * BM, n0 = blockIdx.y * BN;
  int K2 = K - K1;
  float acc[4][4] = {};
  for (int k0 = 0; k0 < K; k0 += BK) {
    {
      int row = t >> 2, kq = (t & 3) * 4;
      int m = m0 + row;
      int kk = k0 + kq;
      float4 a = make_float4(0.f, 0.f, 0.f, 0.f);
      if (m < M) {
        const float* src = (kk < K1) ? (A1 + (size_t)m * K1 + kk)
                                     : (A2 + (size_t)m * K2 + (kk - K1));
        a = *(const float4*)src;
      }
      As[kq + 0][row] = a.x;
      As[kq + 1][row] = a.y;
      As[kq + 2][row] = a.z;
      As[kq + 3][row] = a.w;
      int kb = t >> 4, nq = (t & 15) * 4;
      float4 b = *(const float4*)(B + (size_t)(k0 + kb) * Nc + n0 + nq);
      *(float4*)&Bs[kb][nq] = b;
    }
    __syncthreads();
#pragma unroll
    for (int k = 0; k < BK; k++) {
      float4 a = *(const float4*)&As[k][ty * 4];
      float4 b = *(const float4*)&Bs[k][tx * 4];
      float av[4] = {a.x, a.y, a.z, a.w};
      float bv[4] = {b.x, b.y, b.z, b.w};
#pragma unroll
      for (int i = 0; i < 4; i++)
#pragma unroll
        for (int j = 0; j < 4; j++)
          acc[i][j] = fmaf(av[i], bv[j], acc[i][j]);
    }
    __syncthreads();
  }
#pragma unroll
  for (int i = 0; i < 4; i++) {
    int m = m0 + ty * 4 + i;
    if (m < M) {
      float4 v = make_float4(acc[i][0], acc[i][1], acc[i][2], acc[i][3]);
      *(float4*)(Cout + (size_t)m * Nc + n0 + tx * 4) = v;
    }
  }
}

// ---------------------------------------------------------------------------
// Attention logits, wave-packed: 64/C (n,h)-pairs per wave, xor-reduce.
// ---------------------------------------------------------------------------
template <int H, int C, bool BF>
__global__ void calc_al_kernel(const void* __restrict__ xw, const float* __restrict__ a_src,
                               const float* __restrict__ a_dst, float* __restrict__ alsrc,
                               float* __restrict__ aldst, int NH) {
  constexpr int P = 64 / C;
  int wid = (blockIdx.x * blockDim.x + threadIdx.x) >> 6;
  int lane = threadIdx.x & 63;
  int pair = wid * P + lane / C;
  int c = lane & (C - 1);
  if (pair >= NH) return;
  int h = pair % H;
  float v;
  if (BF) v = bf2f(((const u16*)xw)[(size_t)pair * C + c]);
  else    v = ((const float*)xw)[(size_t)pair * C + c];
  float w1 = v * a_src[h * C + c];
  float w2 = v * a_dst[h * C + c];
#pragma unroll
  for (int st = C / 2; st >= 1; st >>= 1) {
    w1 += __shfl_xor(w1, st);
    w2 += __shfl_xor(w2, st);
  }
  if (c == 0) {
    alsrc[pair] = w1;
    aldst[pair] = w2;
  }
}

// ---------------------------------------------------------------------------
// Layer-1 aggregation, one WAVE per node. H=16, C=64, bf16 rows (2KB).
// Lane covers bf16 cols [16*lane, 16*lane+16) -> head = lane>>2.
// Phase A: online softmax stats, butterfly combine over g=lane&3.
// Phase B: per edge, 2 dwordx4 row loads + 16 FMA; unroll 2.
// ---------------------------------------------------------------------------
__global__ __launch_bounds__(256) void gat_agg1_wave(
    const u16* __restrict__ xwh, const float* __restrict__ alsrc,
    const float* __restrict__ aldst, const int* __restrict__ row_ptr,
    const int* __restrict__ csr_src, const float* __restrict__ bias,
    const float* __restrict__ slope_p, u16* __restrict__ out, int N) {
  int n = blockIdx.x * 4 + (threadIdx.x >> 6);
  if (n >= N) return;
  int lane = threadIdx.x & 63;
  int head = lane >> 2, g = lane & 3;
  float ad = aldst[(size_t)n * 16 + head];
  int start = row_ptr[n];
  int deg = row_ptr[n + 1] - start;

  // phase A: online max+sum per head
  float m = -1e30f, s = 0.f;
  for (int j = g; j < deg; j += 4) {
    int sj = csr_src[start + j];
    float e = lrelu(alsrc[(size_t)sj * 16 + head] + ad);
    float mn = fmaxf(m, e);
    s = s * __expf(m - mn) + __expf(e - mn);
    m = mn;
  }
#pragma unroll
  for (int st = 1; st <= 2; st <<= 1) {
    float m2 = __shfl_xor(m, st);
    float s2 = __shfl_xor(s, st);
    float mn = fmaxf(m, m2);
    s = s * __expf(m - mn) + s2 * __expf(m2 - mn);
    m = mn;
  }
  float rr = 1.f / (s + 1e-16f);

  // phase B: weighted gather
  float acc[16];
#pragma unroll
  for (int i = 0; i < 16; i++) acc[i] = 0.f;

  auto accum = [&](int sj, float w) {
    const u32x4* rp = (const u32x4*)(xwh + (size_t)sj * 1024) + lane * 2;
    u32x4 v0 = rp[0], v1 = rp[1];
#pragma unroll
    for (int i = 0; i < 4; i++) {
      u32 u = v0[i];
      acc[2 * i] = fmaf(w, bf2f(u & 0xffffu), acc[2 * i]);
      acc[2 * i + 1] = fmaf(w, bf2f(u >> 16), acc[2 * i + 1]);
    }
#pragma unroll
    for (int i = 0; i < 4; i++) {
      u32 u = v1[i];
      acc[8 + 2 * i] = fmaf(w, bf2f(u & 0xffffu), acc[8 + 2 * i]);
      acc[8 + 2 * i + 1] = fmaf(w, bf2f(u >> 16), acc[8 + 2 * i + 1]);
    }
  };

  int j = 0;
  for (; j + 2 <= deg; j += 2) {
    int s0 = csr_src[start + j], s1 = csr_src[start + j + 1];
    float w0 = __expf(lrelu(alsrc[(size_t)s0 * 16 + head] + ad) - m) * rr;
    float w1 = __expf(lrelu(alsrc[(size_t)s1 * 16 + head] + ad) - m) * rr;
    accum(s0, w0);
    accum(s1, w1);
  }
  if (j < deg) {
    int s0 = csr_src[start + j];
    float w0 = __expf(lrelu(alsrc[(size_t)s0 * 16 + head] + ad) - m) * rr;
    accum(s0, w0);
  }

  // epilogue: bias + PReLU -> bf16
  float p = slope_p[0];
  u32 ow[8];
#pragma unroll
  for (int i = 0; i < 8; i++) {
    int c = lane * 16 + 2 * i;
    float v0 = acc[2 * i] + bias[c];
    float v1 = acc[2 * i + 1] + bias[c + 1];
    v0 = (v0 >= 0.f) ? v0 : p * v0;
    v1 = (v1 >= 0.f) ? v1 : p * v1;
    ow[i] = (u32)f2bf(v0) | ((u32)f2bf(v1) << 16);
  }
  u32* op = (u32*)(out + (size_t)n * 1024) + lane * 8;
  *(u32x4*)op = *(u32x4*)&ow[0];
  *(u32x4*)(op + 4) = *(u32x4*)&ow[4];
}

// ---------------------------------------------------------------------------
// Layer-2 aggregation, one wave per node. H=8, C=8, fp32 rows (256B).
// Lane = col, head = lane>>3. Unrolled-4 gather.
// ---------------------------------------------------------------------------
__global__ __launch_bounds__(256) void gat_agg2_wave(
    const float* __restrict__ xw, const float* __restrict__ alsrc,
    const float* __restrict__ aldst, const int* __restrict__ row_ptr,
    const int* __restrict__ csr_src, const float* __restrict__ bias,
    const float* __restrict__ slope_p, float* __restrict__ out, int N) {
  int n = blockIdx.x * 4 + (threadIdx.x >> 6);
  if (n >= N) return;
  int lane = threadIdx.x & 63;
  int head = lane >> 3, g = lane & 7;
  float ad = aldst[(size_t)n * 8 + head];
  int start = row_ptr[n];
  int deg = row_ptr[n + 1] - start;

  float m = -1e30f, s = 0.f;
  for (int j = g; j < deg; j += 8) {
    int sj = csr_src[start + j];
    float e = lrelu(alsrc[(size_t)sj * 8 + head] + ad);
    float mn = fmaxf(m, e);
    s = s * __expf(m - mn) + __expf(e - mn);
    m = mn;
  }
#pragma unroll
  for (int st = 1; st <= 4; st <<= 1) {
    float m2 = __shfl_xor(m, st);
    float s2 = __shfl_xor(s, st);
    float mn = fmaxf(m, m2);
    s = s * __expf(m - mn) + s2 * __expf(m2 - mn);
    m = mn;
  }
  float rr = 1.f / (s + 1e-16f);

  float acc = 0.f;
  int j = 0;
  for (; j + 4 <= deg; j += 4) {
    int s0 = csr_src[start + j], s1 = csr_src[start + j + 1];
    int s2i = csr_src[start + j + 2], s3 = csr_src[start + j + 3];
    float w0 = __expf(lrelu(alsrc[(size_t)s0 * 8 + head] + ad) - m) * rr;
    float w1 = __expf(lrelu(alsrc[(size_t)s1 * 8 + head] + ad) - m) * rr;
    float w2 = __expf(lrelu(alsrc[(size_t)s2i * 8 + head] + ad) - m) * rr;
    float w3 = __expf(lrelu(alsrc[(size_t)s3 * 8 + head] + ad) - m) * rr;
    float v0 = xw[(size_t)s0 * 64 + lane];
    float v1 = xw[(size_t)s1 * 64 + lane];
    float v2 = xw[(size_t)s2i * 64 + lane];
    float v3 = xw[(size_t)s3 * 64 + lane];
    acc = fmaf(w0, v0, acc);
    acc = fmaf(w1, v1, acc);
    acc = fmaf(w2, v2, acc);
    acc = fmaf(w3, v3, acc);
  }
  for (; j < deg; j++) {
    int s0 = csr_src[start + j];
    float w0 = __expf(lrelu(alsrc[(size_t)s0 * 8 + head] + ad) - m) * rr;
    acc = fmaf(w0, xw[(size_t)s0 * 64 + lane], acc);
  }

  float p = slope_p[0];
  float v = acc + bias[lane];
  out[(size_t)n * 64 + lane] = (v >= 0.f) ? v : p * v;
}

// ---------------------------------------------------------------------------
// Layer-3 aggregation, one wave per node. H=8, C=16, fp32 rows (512B).
// Lane covers cols (2l, 2l+1), head = lane>>3. Mean over heads + log_softmax.
// ---------------------------------------------------------------------------
__global__ __launch_bounds__(256) void gat_agg3_wave(
    const float* __restrict__ xw, const float* __restrict__ alsrc,
    const float* __restrict__ aldst, const int* __restrict__ row_ptr,
    const int* __restrict__ csr_src, const float* __restrict__ bias,
    float* __restrict__ out, int N) {
  int n = blockIdx.x * 4 + (threadIdx.x >> 6);
  if (n >= N) return;
  int lane = threadIdx.x & 63;
  int head = lane >> 3, g = lane & 7;
  float ad = aldst[(size_t)n * 8 + head];
  int start = row_ptr[n];
  int deg = row_ptr[n + 1] - start;

  float m = -1e30f, s = 0.f;
  for (int j = g; j < deg; j += 8) {
    int sj = csr_src[start + j];
    float e = lrelu(alsrc[(size_t)sj * 8 + head] + ad);
    float mn = fmaxf(m, e);
    s = s * __expf(m - mn) + __expf(e - mn);
    m = mn;
  }
#pragma unroll
  for (int st = 1; st <= 4; st <<= 1) {
    float m2 = __shfl_xor(m, st);
    float s2 = __shfl_xor(s, st);
    float mn = fmaxf(m, m2);
    s = s * __expf(m - mn) + s2 * __expf(m2 - mn);
    m = mn;
  }
  float rr = 1.f / (s + 1e-16f);

  float a0 = 0.f, a1 = 0.f;
  int j = 0;
  for (; j + 2 <= deg; j += 2) {
    int s0 = csr_src[start + j], s1 = csr_src[start + j + 1];
    float w0 = __expf(lrelu(alsrc[(size_t)s0 * 8 + head] + ad) - m) * rr;
    float w1 = __expf(lrelu(alsrc[(size_t)s1 * 8 + head] + ad) - m) * rr;
    float2 v0 = *((const float2*)(xw + (size_t)s0 * 128) + lane);
    float2 v1 = *((const float2*)(xw + (size_t)s1 * 128) + lane);
    a0 = fmaf(w0, v0.x, a0);
    a1 = fmaf(w0, v0.y, a1);
    a0 = fmaf(w1, v1.x, a0);
    a1 = fmaf(w1, v1.y, a1);
  }
  if (j < deg) {
    int s0 = csr_src[start + j];
    float w0 = __expf(lrelu(alsrc[(size_t)s0 * 8 + head] + ad) - m) * rr;
    float2 v0 = *((const float2*)(xw + (size_t)s0 * 128) + lane);
    a0 = fmaf(w0, v0.x, a0);
    a1 = fmaf(w0, v0.y, a1);
  }

  // sum across heads (lanes differing in bits 3..5 hold same (col mod 16))
#pragma unroll
  for (int st = 8; st <= 32; st <<= 1) {
    a0 += __shfl_xor(a0, st);
    a1 += __shfl_xor(a1, st);
  }
  int c0 = (2 * lane) & 15, c1 = (2 * lane + 1) & 15;
  float v0 = a0 * 0.125f + bias[c0];
  float v1 = a1 * 0.125f + bias[c1];
  float mx = fmaxf(v0, v1);
#pragma unroll
  for (int st = 1; st <= 4; st <<= 1) mx = fmaxf(mx, __shfl_xor(mx, st));
  float se = __expf(v0 - mx) + __expf(v1 - mx);
#pragma unroll
  for (int st = 1; st <= 4; st <<= 1) se += __shfl_xor(se, st);
  float lse = mx + logf(se);
  if (lane < 8) {
    float2 o = make_float2(v0 - lse, v1 - lse);
    *((float2*)(out + (size_t)n * 16) + lane) = o;
  }
}

// ---------------------------------------------------------------------------
extern "C" void kernel_launch(void* const* d_in, const int* in_sizes, int n_in,
                              void* d_out, int out_size, void* d_ws, size_t ws_size,
                              hipStream_t stream) {
  const float* x        = (const float*)d_in[0];
  const int*   ei       = (const int*)d_in[1];
  const float* bn_gamma = (const float*)d_in[2];
  const float* bn_beta  = (const float*)d_in[3];
  const float* W1       = (const float*)d_in[4];
  const float* a1s      = (const float*)d_in[5];
  const float* a1d      = (const float*)d_in[6];
  const float* b1       = (const float*)d_in[7];
  const float* p1       = (const float*)d_in[8];
  const float* W2       = (const float*)d_in[9];
  const float* a2s      = (const float*)d_in[10];
  const float* a2d      = (const float*)d_in[11];
  const float* b2       = (const float*)d_in[12];
  const float* p2       = (const float*)d_in[13];
  const float* W3       = (const float*)d_in[14];
  const float* a3s      = (const float*)d_in[15];
  const float* a3d      = (const float*)d_in[16];
  const float* b3       = (const float*)d_in[17];
  float* out = (float*)d_out;

  const int F  = in_sizes[2];       // 256
  const int N  = in_sizes[0] / F;   // 20000
  const int E  = in_sizes[1] / 2;   // 320000
  const int ET = E + N;
  const int MP = ((N + 127) / 128) * 128;  // MFMA row padding

  size_t off = 0;
  auto alloc = [&](size_t bytes) -> char* {
    char* r = (char*)d_ws + off;
    off += (bytes + 255) & ~(size_t)255;
    return r;
  };
  float* musum   = (float*)alloc(F * 4);
  float* sqsum   = (float*)alloc(F * 4);
  float* scale   = (float*)alloc(F * 4);
  float* shift   = (float*)alloc(F * 4);
  int*   row_ptr = (int*)alloc((size_t)(N + 1) * 4);
  int*   cursor  = (int*)alloc((size_t)N * 4);
  int*   csr_src = (int*)alloc((size_t)ET * 4);
  float* al_s    = (float*)alloc((size_t)N * 16 * 4);
  float* al_d    = (float*)alloc((size_t)N * 16 * 4);
  u16*   Wt1     = (u16*)alloc((size_t)256 * 1024 * 2);
  u16*   Wt2     = (u16*)alloc((size_t)1280 * 64 * 2);
  u16*   x_in_h  = (u16*)alloc((size_t)MP * 256 * 2);
  u16*   xw1h    = (u16*)alloc((size_t)MP * 1024 * 2);
  u16*   h1      = (u16*)alloc((size_t)MP * 1024 * 2);
  float* xw2     = (float*)alloc((size_t)MP * 64 * 4);
  float* h2      = (float*)alloc((size_t)MP * 64 * 4);
  float* xw3     = (float*)alloc((size_t)MP * 128 * 4);

  // ---- BatchNorm ----
  hipMemsetAsync(musum, 0, (size_t)2 * F * 4, stream);
  bn_stats_kernel<<<256, 256, 0, stream>>>(x, musum, sqsum, N, F);
  bn_finalize_kernel<<<1, F, 0, stream>>>(musum, sqsum, bn_gamma, bn_beta, scale, shift, N);
  int totalXF = N * F;
  bn_apply_bf16_kernel<<<(totalXF + 255) / 256, 256, 0, stream>>>(x, scale, shift, x_in_h,
                                                                  totalXF, F - 1);

  // ---- CSR by dst ----
  hipMemsetAsync(cursor, 0, (size_t)N * 4, stream);
  csr_count_kernel<<<(ET + 255) / 256, 256, 0, stream>>>(ei, E, N, cursor);
  csr_scan_kernel<<<1, 256, 0, stream>>>(cursor, row_ptr, cursor, N);
  csr_fill_kernel<<<(ET + 255) / 256, 256, 0, stream>>>(ei, E, N, cursor, csr_src);

  // ---- weight pre-fragmentation ----
  wt_build_kernel<<<(256 * 1024 + 255) / 256, 256, 0, stream>>>(W1, Wt1, 256, 1024);
  wt_build_kernel<<<(1280 * 64 + 255) / 256, 256, 0, stream>>>(W2, Wt2, 1280, 64);

  int nblk = (N + 3) / 4;  // 4 wave-nodes per 256-block

  // ---- Layer 1: [N,256]@[256,1024] MFMA (bf16 out only), H=16, C=64 ----
  {
    dim3 grid(MP / 128, 1024 / 128);
    mfma_gemm_kernel<128, 128, 4, 4, false, true><<<grid, 256, 0, stream>>>(
        x_in_h, x_in_h, 256, 256, Wt1, nullptr, xw1h, N, 1024);
    int NH = N * 16;  // P=1 -> NH waves
    calc_al_kernel<16, 64, true><<<(NH + 3) / 4, 256, 0, stream>>>(xw1h, a1s, a1d, al_s, al_d, NH);
    gat_agg1_wave<<<nblk, 256, 0, stream>>>(xw1h, al_s, al_d, row_ptr, csr_src, b1, p1, h1, N);
  }

  // ---- Layer 2: concat([x_in,h1]) [N,1280]@[1280,64] MFMA, H=8, C=8 ----
  {
    dim3 grid((N + 63) / 64, 1);
    mfma_gemm_kernel<64, 64, 2, 2, true, false><<<grid, 256, 0, stream>>>(
        x_in_h, h1, 256, 1280, Wt2, xw2, nullptr, N, 64);
    int NH = N * 8;  // P=8 -> NH/8 waves
    int waves = (NH + 7) / 8;
    calc_al_kernel<8, 8, false><<<(waves + 3) / 4, 256, 0, stream>>>(xw2, a2s, a2d, al_s, al_d, NH);
    gat_agg2_wave<<<nblk, 256, 0, stream>>>(xw2, al_s, al_d, row_ptr, csr_src, b2, p2, h2, N);
  }

  // ---- Layer 3: [N,64]@[64,128] fp32, H=8, C=16, mean + log_softmax ----
  {
    dim3 grid((N + 63) / 64, 128 / 64);
    gemm_kernel<<<grid, 256, 0, stream>>>(h2, h2, 64, 64, W3, xw3, N, 128);
    int NH = N * 8;  // P=4 -> NH/4 waves
    int waves = (NH + 3) / 4;
    calc_al_kernel<8, 16, false><<<(waves + 3) / 4, 256, 0, stream>>>(xw3, a3s, a3d, al_s, al_d, NH);
    gat_agg3_wave<<<nblk, 256, 0, stream>>>(xw3, al_s, al_d, row_ptr, csr_src, b3, out, N);
  }
}

// Round 4
// 379.755 us; speedup vs baseline: 1.8933x; 1.0492x over previous
//
#include <hip/hip_runtime.h>
#include <math.h>

typedef unsigned int u32;
typedef unsigned short u16;
typedef u32 u32x4 __attribute__((ext_vector_type(4)));
typedef float f32x4 __attribute__((ext_vector_type(4)));

__device__ __forceinline__ u16 f2bf(float f) {
  u32 u = __builtin_bit_cast(u32, f);
  return (u16)((u + 0x7FFFu + ((u >> 16) & 1u)) >> 16);
}
__device__ __forceinline__ float bf2f(u32 lo16) {
  return __builtin_bit_cast(float, lo16 << 16);
}
__device__ __forceinline__ void mfma16(f32x4& c, const u32x4& a, const u32x4& b) {
  asm volatile("v_mfma_f32_16x16x32_bf16 %0, %1, %2, %0" : "+v"(c) : "v"(a), "v"(b));
}
__device__ __forceinline__ float lrelu(float e) { return (e >= 0.f) ? e : 0.2f * e; }

// ---------------------------------------------------------------------------
// BatchNorm
// ---------------------------------------------------------------------------
__global__ void bn_stats_kernel(const float* __restrict__ x, float* __restrict__ musum,
                                float* __restrict__ sqsum, int N, int F) {
  int t = threadIdx.x;  // F == 256
  float s = 0.f, s2 = 0.f;
  for (int r = blockIdx.x; r < N; r += gridDim.x) {
    float v = x[(size_t)r * F + t];
    s += v;
    s2 += v * v;
  }
  atomicAdd(&musum[t], s);
  atomicAdd(&sqsum[t], s2);
}

__global__ void bn_finalize_kernel(const float* __restrict__ musum, const float* __restrict__ sqsum,
                                   const float* __restrict__ gamma, const float* __restrict__ beta,
                                   float* __restrict__ scale, float* __restrict__ shift, int N) {
  int t = threadIdx.x;
  float m = musum[t] / (float)N;
  float v = sqsum[t] / (float)N - m * m;
  float sc = gamma[t] * rsqrtf(v + 1e-5f);
  scale[t] = sc;
  shift[t] = beta[t] - m * sc;
}

__global__ void bn_apply_bf16_kernel(const float* __restrict__ x, const float* __restrict__ scale,
                                     const float* __restrict__ shift, u16* __restrict__ xin,
                                     int total, int Fmask) {
  int i = blockIdx.x * blockDim.x + threadIdx.x;
  if (i < total) {
    int c = i & Fmask;
    xin[i] = f2bf(x[i] * scale[c] + shift[c]);
  }
}

// ---------------------------------------------------------------------------
// CSR build (dst-indexed)
// ---------------------------------------------------------------------------
__global__ void csr_count_kernel(const int* __restrict__ ei, int E, int N, int* __restrict__ cnt) {
  int e = blockIdx.x * blockDim.x + threadIdx.x;
  int ET = E + N;
  if (e < ET) {
    int d = (e < E) ? ei[E + e] : (e - E);
    atomicAdd(&cnt[d], 1);
  }
}

__global__ void csr_scan_kernel(const int* __restrict__ cnt, int* __restrict__ row_ptr,
                                int* __restrict__ cursor, int N) {
  __shared__ int part[256];
  int t = threadIdx.x;
  int chunk = (N + 255) / 256;
  int lo = t * chunk;
  int hi = min(lo + chunk, N);
  int s = 0;
  for (int i = lo; i < hi; i++) s += cnt[i];
  part[t] = s;
  __syncthreads();
  for (int off = 1; off < 256; off <<= 1) {
    int v = (t >= off) ? part[t - off] : 0;
    __syncthreads();
    part[t] += v;
    __syncthreads();
  }
  int run = (t == 0) ? 0 : part[t - 1];
  for (int i = lo; i < hi; i++) {
    row_ptr[i] = run;
    cursor[i] = run;
    run += cnt[i];
  }
  if (t == 255) row_ptr[N] = part[255];
}

__global__ void csr_fill_kernel(const int* __restrict__ ei, int E, int N,
                                int* __restrict__ cursor, int* __restrict__ csr_src) {
  int e = blockIdx.x * blockDim.x + threadIdx.x;
  int ET = E + N;
  if (e < ET) {
    int s, d;
    if (e < E) { s = ei[e]; d = ei[E + e]; }
    else       { s = e - E; d = s; }
    int pos = atomicAdd(&cursor[d], 1);
    csr_src[pos] = s;
  }
}

// ---------------------------------------------------------------------------
// Merged weight pre-fragmentation: W fp32 [K][Nc] -> Wt bf16 [Nc][K]
// ---------------------------------------------------------------------------
__global__ void wt_build_all(const float* __restrict__ W1, const float* __restrict__ W2,
                             const float* __restrict__ W3, u16* __restrict__ Wt1,
                             u16* __restrict__ Wt2, u16* __restrict__ Wt3) {
  const int S1 = 256 * 1024, S2 = 1280 * 64, S3 = 64 * 128;
  int idx = blockIdx.x * blockDim.x + threadIdx.x;
  if (idx < S1) {
    int n = idx / 256, k = idx % 256;
    Wt1[idx] = f2bf(W1[(size_t)k * 1024 + n]);
  } else if (idx < S1 + S2) {
    int i = idx - S1;
    int n = i / 1280, k = i % 1280;
    Wt2[i] = f2bf(W2[(size_t)k * 64 + n]);
  } else if (idx < S1 + S2 + S3) {
    int i = idx - S1 - S2;
    int n = i / 64, k = i % 64;
    Wt3[i] = f2bf(W3[(size_t)k * 128 + n]);
  }
}

// ---------------------------------------------------------------------------
// bf16 MFMA GEMM. A as two bf16 row-major segments (K1 | K-K1), Wt [Nc][K].
// 4 waves 2x2, wave tile (FM*16)x(FN*16), BK=32. WF fp32 out / WH bf16 out.
// ---------------------------------------------------------------------------
template <int BM, int BN, int FM, int FN, bool WF, bool WH>
__global__ __launch_bounds__(256) void mfma_gemm_kernel(
    const u16* __restrict__ A1, const u16* __restrict__ A2, int K1, int K,
    const u16* __restrict__ Wt, float* __restrict__ Cf, u16* __restrict__ Ch,
    int M, int Nc) {
  constexpr int BK = 32;
  constexpr int CA = (BM * BK) / (256 * 8);
  constexpr int CB = (BN * BK) / (256 * 8);
  static_assert(BM == 2 * FM * 16 && BN == 2 * FN * 16, "wave grid 2x2");
  __shared__ u16 As[BM * BK];
  __shared__ u16 Bs[BN * BK];
  int t = threadIdx.x;
  int m0 = blockIdx.x * BM, n0 = blockIdx.y * BN;
  int r = t & 15;
  int g = (t >> 4) & 3;
  int wid = t >> 6;
  int wm0 = (wid >> 1) * (FM * 16);
  int wn0 = (wid & 1) * (FN * 16);
  int K8 = K >> 3;
  int K2 = K - K1;

  f32x4 acc[FM][FN] = {};
  asm volatile("s_nop 7\n\ts_nop 7" :::);  // VALU acc-init -> MFMA SrcC hazard guard

  for (int k0 = 0; k0 < K; k0 += BK) {
    const u16* Aseg;
    int sA, kl;
    if (k0 < K1) { Aseg = A1; sA = K1; kl = k0; }
    else         { Aseg = A2; sA = K2; kl = k0 - K1; }
    __syncthreads();
#pragma unroll
    for (int i = 0; i < CA; i++) {
      int c = i * 256 + t;
      int m = c >> 2, kb = c & 3;
      *(u32x4*)(As + c * 8) =
          *(const u32x4*)(Aseg + (size_t)(m0 + m) * sA + kl + kb * 8);
    }
#pragma unroll
    for (int i = 0; i < CB; i++) {
      int c = i * 256 + t;
      int nn = c >> 2, kb = c & 3;
      *(u32x4*)(Bs + c * 8) =
          *(const u32x4*)(Wt + ((size_t)(n0 + nn) * K8 + (k0 >> 3) + kb) * 8);
    }
    __syncthreads();
    u32x4 af[FM], bfr[FN];
#pragma unroll
    for (int fi = 0; fi < FM; fi++)
      af[fi] = *(const u32x4*)(As + ((wm0 + fi * 16 + r) * 4 + g) * 8);
#pragma unroll
    for (int fj = 0; fj < FN; fj++)
      bfr[fj] = *(const u32x4*)(Bs + ((wn0 + fj * 16 + r) * 4 + g) * 8);
#pragma unroll
    for (int fi = 0; fi < FM; fi++)
#pragma unroll
      for (int fj = 0; fj < FN; fj++) mfma16(acc[fi][fj], af[fi], bfr[fj]);
  }
  asm volatile("s_nop 7\n\ts_nop 7" :::);  // MFMA -> VALU read hazard guard

#pragma unroll
  for (int fi = 0; fi < FM; fi++) {
#pragma unroll
    for (int fj = 0; fj < FN; fj++) {
#pragma unroll
      for (int v = 0; v < 4; v++) {
        int m = m0 + wm0 + fi * 16 + g * 4 + v;
        int nn = n0 + wn0 + fj * 16 + r;
        if (m < M) {
          float val = acc[fi][fj][v];
          if (WF) Cf[(size_t)m * Nc + nn] = val;
          if (WH) Ch[(size_t)m * Nc + nn] = f2bf(val);
        }
      }
    }
  }
}

// ---------------------------------------------------------------------------
// Attention logits, wave-packed: 64/C (n,h)-pairs per wave, xor-reduce.
// ---------------------------------------------------------------------------
template <int H, int C, bool BF>
__global__ void calc_al_kernel(const void* __restrict__ xw, const float* __restrict__ a_src,
                               const float* __restrict__ a_dst, float* __restrict__ alsrc,
                               float* __restrict__ aldst, int NH) {
  constexpr int P = 64 / C;
  int wid = (blockIdx.x * blockDim.x + threadIdx.x) >> 6;
  int lane = threadIdx.x & 63;
  int pair = wid * P + lane / C;
  int c = lane & (C - 1);
  if (pair >= NH) return;
  int h = pair % H;
  float v;
  if (BF) v = bf2f(((const u16*)xw)[(size_t)pair * C + c]);
  else    v = ((const float*)xw)[(size_t)pair * C + c];
  float w1 = v * a_src[h * C + c];
  float w2 = v * a_dst[h * C + c];
#pragma unroll
  for (int st = C / 2; st >= 1; st >>= 1) {
    w1 += __shfl_xor(w1, st);
    w2 += __shfl_xor(w2, st);
  }
  if (c == 0) {
    alsrc[pair] = w1;
    aldst[pair] = w2;
  }
}

// ---------------------------------------------------------------------------
// Layer-1 aggregation: TWO waves per node (half row of 512 bf16 cols each),
// unroll-4 pipelined gather. head = q*8 + lane/8, 8 lanes per head.
// ---------------------------------------------------------------------------
__global__ __launch_bounds__(256) void gat_agg1_wave(
    const u16* __restrict__ xwh, const float* __restrict__ alsrc,
    const float* __restrict__ aldst, const int* __restrict__ row_ptr,
    const int* __restrict__ csr_src, const float* __restrict__ bias,
    const float* __restrict__ slope_p, u16* __restrict__ out, int N) {
  int wid = blockIdx.x * 4 + (threadIdx.x >> 6);
  int n = wid >> 1, q = wid & 1;
  if (n >= N) return;
  int lane = threadIdx.x & 63;
  int head = q * 8 + (lane >> 3), g = lane & 7;
  float ad = aldst[(size_t)n * 16 + head];
  int start = row_ptr[n];
  int deg = row_ptr[n + 1] - start;

  // phase A: online softmax stats (8 lanes per head)
  float m = -1e30f, s = 0.f;
  for (int j = g; j < deg; j += 8) {
    int sj = csr_src[start + j];
    float e = lrelu(alsrc[(size_t)sj * 16 + head] + ad);
    float mn = fmaxf(m, e);
    s = s * __expf(m - mn) + __expf(e - mn);
    m = mn;
  }
#pragma unroll
  for (int st = 1; st <= 4; st <<= 1) {
    float m2 = __shfl_xor(m, st);
    float s2 = __shfl_xor(s, st);
    float mn = fmaxf(m, m2);
    s = s * __expf(m - mn) + s2 * __expf(m2 - mn);
    m = mn;
  }
  float rr = 1.f / (s + 1e-16f);

  // phase B: weighted gather, 4 edges in flight
  float acc[8] = {};
  const u16* base = xwh + (size_t)q * 512 + (size_t)lane * 8;

  auto wcalc = [&](int sj) {
    return __expf(lrelu(alsrc[(size_t)sj * 16 + head] + ad) - m) * rr;
  };
  auto fma8 = [&](u32x4 v, float w) {
#pragma unroll
    for (int i = 0; i < 4; i++) {
      u32 u = v[i];
      acc[2 * i] = fmaf(w, bf2f(u & 0xffffu), acc[2 * i]);
      acc[2 * i + 1] = fmaf(w, bf2f(u >> 16), acc[2 * i + 1]);
    }
  };

  int j = 0;
  for (; j + 4 <= deg; j += 4) {
    int s0 = csr_src[start + j], s1 = csr_src[start + j + 1];
    int s2i = csr_src[start + j + 2], s3 = csr_src[start + j + 3];
    u32x4 v0 = *(const u32x4*)(base + (size_t)s0 * 1024);
    u32x4 v1 = *(const u32x4*)(base + (size_t)s1 * 1024);
    u32x4 v2 = *(const u32x4*)(base + (size_t)s2i * 1024);
    u32x4 v3 = *(const u32x4*)(base + (size_t)s3 * 1024);
    float w0 = wcalc(s0), w1 = wcalc(s1), w2 = wcalc(s2i), w3 = wcalc(s3);
    fma8(v0, w0);
    fma8(v1, w1);
    fma8(v2, w2);
    fma8(v3, w3);
  }
  for (; j < deg; j++) {
    int s0 = csr_src[start + j];
    u32x4 v0 = *(const u32x4*)(base + (size_t)s0 * 1024);
    fma8(v0, wcalc(s0));
  }

  // epilogue: bias + PReLU -> bf16
  float p = slope_p[0];
  u32 ow[4];
#pragma unroll
  for (int i = 0; i < 4; i++) {
    int c = q * 512 + lane * 8 + 2 * i;
    float v0 = acc[2 * i] + bias[c];
    float v1 = acc[2 * i + 1] + bias[c + 1];
    v0 = (v0 >= 0.f) ? v0 : p * v0;
    v1 = (v1 >= 0.f) ? v1 : p * v1;
    ow[i] = (u32)f2bf(v0) | ((u32)f2bf(v1) << 16);
  }
  *(u32x4*)((u32*)(out + (size_t)n * 1024 + q * 512) + lane * 4) = *(u32x4*)ow;
}

// ---------------------------------------------------------------------------
// Layer-2 aggregation, one wave per node. H=8, C=8, bf16 rows (128B).
// ---------------------------------------------------------------------------
__global__ __launch_bounds__(256) void gat_agg2_wave(
    const u16* __restrict__ xwh, const float* __restrict__ alsrc,
    const float* __restrict__ aldst, const int* __restrict__ row_ptr,
    const int* __restrict__ csr_src, const float* __restrict__ bias,
    const float* __restrict__ slope_p, u16* __restrict__ out, int N) {
  int n = blockIdx.x * 4 + (threadIdx.x >> 6);
  if (n >= N) return;
  int lane = threadIdx.x & 63;
  int head = lane >> 3, g = lane & 7;
  float ad = aldst[(size_t)n * 8 + head];
  int start = row_ptr[n];
  int deg = row_ptr[n + 1] - start;

  float m = -1e30f, s = 0.f;
  for (int j = g; j < deg; j += 8) {
    int sj = csr_src[start + j];
    float e = lrelu(alsrc[(size_t)sj * 8 + head] + ad);
    float mn = fmaxf(m, e);
    s = s * __expf(m - mn) + __expf(e - mn);
    m = mn;
  }
#pragma unroll
  for (int st = 1; st <= 4; st <<= 1) {
    float m2 = __shfl_xor(m, st);
    float s2 = __shfl_xor(s, st);
    float mn = fmaxf(m, m2);
    s = s * __expf(m - mn) + s2 * __expf(m2 - mn);
    m = mn;
  }
  float rr = 1.f / (s + 1e-16f);

  float acc = 0.f;
  int j = 0;
  for (; j + 4 <= deg; j += 4) {
    int s0 = csr_src[start + j], s1 = csr_src[start + j + 1];
    int s2i = csr_src[start + j + 2], s3 = csr_src[start + j + 3];
    float v0 = bf2f(xwh[(size_t)s0 * 64 + lane]);
    float v1 = bf2f(xwh[(size_t)s1 * 64 + lane]);
    float v2 = bf2f(xwh[(size_t)s2i * 64 + lane]);
    float v3 = bf2f(xwh[(size_t)s3 * 64 + lane]);
    float w0 = __expf(lrelu(alsrc[(size_t)s0 * 8 + head] + ad) - m) * rr;
    float w1 = __expf(lrelu(alsrc[(size_t)s1 * 8 + head] + ad) - m) * rr;
    float w2 = __expf(lrelu(alsrc[(size_t)s2i * 8 + head] + ad) - m) * rr;
    float w3 = __expf(lrelu(alsrc[(size_t)s3 * 8 + head] + ad) - m) * rr;
    acc = fmaf(w0, v0, acc);
    acc = fmaf(w1, v1, acc);
    acc = fmaf(w2, v2, acc);
    acc = fmaf(w3, v3, acc);
  }
  for (; j < deg; j++) {
    int s0 = csr_src[start + j];
    float w0 = __expf(lrelu(alsrc[(size_t)s0 * 8 + head] + ad) - m) * rr;
    acc = fmaf(w0, bf2f(xwh[(size_t)s0 * 64 + lane]), acc);
  }

  float p = slope_p[0];
  float v = acc + bias[lane];
  out[(size_t)n * 64 + lane] = f2bf((v >= 0.f) ? v : p * v);
}

// ---------------------------------------------------------------------------
// Layer-3 aggregation, one wave per node. H=8, C=16, bf16 rows (256B).
// Lane covers cols (2l, 2l+1) via one u32 load. Mean over heads + log_softmax.
// ---------------------------------------------------------------------------
__global__ __launch_bounds__(256) void gat_agg3_wave(
    const u16* __restrict__ xwh, const float* __restrict__ alsrc,
    const float* __restrict__ aldst, const int* __restrict__ row_ptr,
    const int* __restrict__ csr_src, const float* __restrict__ bias,
    float* __restrict__ out, int N) {
  int n = blockIdx.x * 4 + (threadIdx.x >> 6);
  if (n >= N) return;
  int lane = threadIdx.x & 63;
  int head = lane >> 3, g = lane & 7;
  float ad = aldst[(size_t)n * 8 + head];
  int start = row_ptr[n];
  int deg = row_ptr[n + 1] - start;

  float m = -1e30f, s = 0.f;
  for (int j = g; j < deg; j += 8) {
    int sj = csr_src[start + j];
    float e = lrelu(alsrc[(size_t)sj * 8 + head] + ad);
    float mn = fmaxf(m, e);
    s = s * __expf(m - mn) + __expf(e - mn);
    m = mn;
  }
#pragma unroll
  for (int st = 1; st <= 4; st <<= 1) {
    float m2 = __shfl_xor(m, st);
    float s2 = __shfl_xor(s, st);
    float mn = fmaxf(m, m2);
    s = s * __expf(m - mn) + s2 * __expf(m2 - mn);
    m = mn;
  }
  float rr = 1.f / (s + 1e-16f);

  float a0 = 0.f, a1 = 0.f;
  int j = 0;
  for (; j + 4 <= deg; j += 4) {
    int s0 = csr_src[start + j], s1 = csr_src[start + j + 1];
    int s2i = csr_src[start + j + 2], s3 = csr_src[start + j + 3];
    u32 v0 = *(const u32*)(xwh + (size_t)s0 * 128 + lane * 2);
    u32 v1 = *(const u32*)(xwh + (size_t)s1 * 128 + lane * 2);
    u32 v2 = *(const u32*)(xwh + (size_t)s2i * 128 + lane * 2);
    u32 v3 = *(const u32*)(xwh + (size_t)s3 * 128 + lane * 2);
    float w0 = __expf(lrelu(alsrc[(size_t)s0 * 8 + head] + ad) - m) * rr;
    float w1 = __expf(lrelu(alsrc[(size_t)s1 * 8 + head] + ad) - m) * rr;
    float w2 = __expf(lrelu(alsrc[(size_t)s2i * 8 + head] + ad) - m) * rr;
    float w3 = __expf(lrelu(alsrc[(size_t)s3 * 8 + head] + ad) - m) * rr;
    a0 = fmaf(w0, bf2f(v0 & 0xffffu), a0);
    a1 = fmaf(w0, bf2f(v0 >> 16), a1);
    a0 = fmaf(w1, bf2f(v1 & 0xffffu), a0);
    a1 = fmaf(w1, bf2f(v1 >> 16), a1);
    a0 = fmaf(w2, bf2f(v2 & 0xffffu), a0);
    a1 = fmaf(w2, bf2f(v2 >> 16), a1);
    a0 = fmaf(w3, bf2f(v3 & 0xffffu), a0);
    a1 = fmaf(w3, bf2f(v3 >> 16), a1);
  }
  for (; j < deg; j++) {
    int s0 = csr_src[start + j];
    u32 v0 = *(const u32*)(xwh + (size_t)s0 * 128 + lane * 2);
    float w0 = __expf(lrelu(alsrc[(size_t)s0 * 8 + head] + ad) - m) * rr;
    a0 = fmaf(w0, bf2f(v0 & 0xffffu), a0);
    a1 = fmaf(w0, bf2f(v0 >> 16), a1);
  }

  // sum across heads (bits 3..5 of lane index select the head)
#pragma unroll
  for (int st = 8; st <= 32; st <<= 1) {
    a0 += __shfl_xor(a0, st);
    a1 += __shfl_xor(a1, st);
  }
  int c0 = (2 * lane) & 15, c1 = (2 * lane + 1) & 15;
  float v0 = a0 * 0.125f + bias[c0];
  float v1 = a1 * 0.125f + bias[c1];
  float mx = fmaxf(v0, v1);
#pragma unroll
  for (int st = 1; st <= 4; st <<= 1) mx = fmaxf(mx, __shfl_xor(mx, st));
  float se = __expf(v0 - mx) + __expf(v1 - mx);
#pragma unroll
  for (int st = 1; st <= 4; st <<= 1) se += __shfl_xor(se, st);
  float lse = mx + logf(se);
  if (lane < 8) {
    float2 o = make_float2(v0 - lse, v1 - lse);
    *((float2*)(out + (size_t)n * 16) + lane) = o;
  }
}

// ---------------------------------------------------------------------------
extern "C" void kernel_launch(void* const* d_in, const int* in_sizes, int n_in,
                              void* d_out, int out_size, void* d_ws, size_t ws_size,
                              hipStream_t stream) {
  const float* x        = (const float*)d_in[0];
  const int*   ei       = (const int*)d_in[1];
  const float* bn_gamma = (const float*)d_in[2];
  const float* bn_beta  = (const float*)d_in[3];
  const float* W1       = (const float*)d_in[4];
  const float* a1s      = (const float*)d_in[5];
  const float* a1d      = (const float*)d_in[6];
  const float* b1       = (const float*)d_in[7];
  const float* p1       = (const float*)d_in[8];
  const float* W2       = (const float*)d_in[9];
  const float* a2s      = (const float*)d_in[10];
  const float* a2d      = (const float*)d_in[11];
  const float* b2       = (const float*)d_in[12];
  const float* p2       = (const float*)d_in[13];
  const float* W3       = (const float*)d_in[14];
  const float* a3s      = (const float*)d_in[15];
  const float* a3d      = (const float*)d_in[16];
  const float* b3       = (const float*)d_in[17];
  float* out = (float*)d_out;

  const int F  = in_sizes[2];       // 256
  const int N  = in_sizes[0] / F;   // 20000
  const int E  = in_sizes[1] / 2;   // 320000
  const int ET = E + N;
  const int MP = ((N + 127) / 128) * 128;  // MFMA row padding

  size_t off = 0;
  auto alloc = [&](size_t bytes) -> char* {
    char* r = (char*)d_ws + off;
    off += (bytes + 255) & ~(size_t)255;
    return r;
  };
  float* musum   = (float*)alloc(F * 4);
  float* sqsum   = (float*)alloc(F * 4);
  float* scale   = (float*)alloc(F * 4);
  float* shift   = (float*)alloc(F * 4);
  int*   row_ptr = (int*)alloc((size_t)(N + 1) * 4);
  int*   cursor  = (int*)alloc((size_t)N * 4);
  int*   csr_src = (int*)alloc((size_t)ET * 4);
  float* al_s    = (float*)alloc((size_t)N * 16 * 4);
  float* al_d    = (float*)alloc((size_t)N * 16 * 4);
  u16*   Wt1     = (u16*)alloc((size_t)256 * 1024 * 2);
  u16*   Wt2     = (u16*)alloc((size_t)1280 * 64 * 2);
  u16*   Wt3     = (u16*)alloc((size_t)64 * 128 * 2);
  u16*   x_in_h  = (u16*)alloc((size_t)MP * 256 * 2);
  u16*   xw1h    = (u16*)alloc((size_t)MP * 1024 * 2);
  u16*   h1      = (u16*)alloc((size_t)MP * 1024 * 2);
  u16*   xw2h    = (u16*)alloc((size_t)MP * 64 * 2);
  u16*   h2h     = (u16*)alloc((size_t)MP * 64 * 2);
  u16*   xw3h    = (u16*)alloc((size_t)MP * 128 * 2);

  // ---- BatchNorm ----
  hipMemsetAsync(musum, 0, (size_t)2 * F * 4, stream);
  bn_stats_kernel<<<256, 256, 0, stream>>>(x, musum, sqsum, N, F);
  bn_finalize_kernel<<<1, F, 0, stream>>>(musum, sqsum, bn_gamma, bn_beta, scale, shift, N);
  int totalXF = N * F;
  bn_apply_bf16_kernel<<<(totalXF + 255) / 256, 256, 0, stream>>>(x, scale, shift, x_in_h,
                                                                  totalXF, F - 1);

  // ---- CSR by dst ----
  hipMemsetAsync(cursor, 0, (size_t)N * 4, stream);
  csr_count_kernel<<<(ET + 255) / 256, 256, 0, stream>>>(ei, E, N, cursor);
  csr_scan_kernel<<<1, 256, 0, stream>>>(cursor, row_ptr, cursor, N);
  csr_fill_kernel<<<(ET + 255) / 256, 256, 0, stream>>>(ei, E, N, cursor, csr_src);

  // ---- weight pre-fragmentation (merged) ----
  {
    int total = 256 * 1024 + 1280 * 64 + 64 * 128;
    wt_build_all<<<(total + 255) / 256, 256, 0, stream>>>(W1, W2, W3, Wt1, Wt2, Wt3);
  }

  int nblk = (N + 3) / 4;

  // ---- Layer 1: [N,256]@[256,1024] MFMA bf16, H=16, C=64 ----
  {
    dim3 grid(MP / 128, 1024 / 128);
    mfma_gemm_kernel<128, 128, 4, 4, false, true><<<grid, 256, 0, stream>>>(
        x_in_h, x_in_h, 256, 256, Wt1, nullptr, xw1h, N, 1024);
    int NH = N * 16;  // P=1
    calc_al_kernel<16, 64, true><<<(NH + 3) / 4, 256, 0, stream>>>(xw1h, a1s, a1d, al_s, al_d, NH);
    gat_agg1_wave<<<(2 * N + 3) / 4, 256, 0, stream>>>(xw1h, al_s, al_d, row_ptr, csr_src, b1, p1,
                                                       h1, N);
  }

  // ---- Layer 2: concat([x_in,h1]) [N,1280]@[1280,64] MFMA bf16, H=8, C=8 ----
  {
    dim3 grid((N + 63) / 64, 1);
    mfma_gemm_kernel<64, 64, 2, 2, false, true><<<grid, 256, 0, stream>>>(
        x_in_h, h1, 256, 1280, Wt2, nullptr, xw2h, N, 64);
    int NH = N * 8;  // P=8
    int waves = (NH + 7) / 8;
    calc_al_kernel<8, 8, true><<<(waves + 3) / 4, 256, 0, stream>>>(xw2h, a2s, a2d, al_s, al_d, NH);
    gat_agg2_wave<<<nblk, 256, 0, stream>>>(xw2h, al_s, al_d, row_ptr, csr_src, b2, p2, h2h, N);
  }

  // ---- Layer 3: [N,64]@[64,128] MFMA bf16, H=8, C=16, mean + log_softmax ----
  {
    dim3 grid((N + 63) / 64, 128 / 64);
    mfma_gemm_kernel<64, 64, 2, 2, false, true><<<grid, 256, 0, stream>>>(
        h2h, h2h, 64, 64, Wt3, nullptr, xw3h, N, 128);
    int NH = N * 8;  // P=4
    int waves = (NH + 3) / 4;
    calc_al_kernel<8, 16, true><<<(waves + 3) / 4, 256, 0, stream>>>(xw3h, a3s, a3d, al_s, al_d, NH);
    gat_agg3_wave<<<nblk, 256, 0, stream>>>(xw3h, al_s, al_d, row_ptr, csr_src, b3, out, N);
  }
}

// Round 5
// 368.430 us; speedup vs baseline: 1.9515x; 1.0307x over previous
//
#include <hip/hip_runtime.h>
#include <math.h>

typedef unsigned int u32;
typedef unsigned short u16;
typedef u32 u32x4 __attribute__((ext_vector_type(4)));
typedef float f32x4 __attribute__((ext_vector_type(4)));

__device__ __forceinline__ u16 f2bf(float f) {
  u32 u = __builtin_bit_cast(u32, f);
  return (u16)((u + 0x7FFFu + ((u >> 16) & 1u)) >> 16);
}
__device__ __forceinline__ float bf2f(u32 lo16) {
  return __builtin_bit_cast(float, lo16 << 16);
}
__device__ __forceinline__ void mfma16(f32x4& c, const u32x4& a, const u32x4& b) {
  asm volatile("v_mfma_f32_16x16x32_bf16 %0, %1, %2, %0" : "+v"(c) : "v"(a), "v"(b));
}
__device__ __forceinline__ float lrelu(float e) { return fmaxf(e, 0.2f * e); }

// ---------------------------------------------------------------------------
// BatchNorm
// ---------------------------------------------------------------------------
__global__ void bn_stats_kernel(const float* __restrict__ x, float* __restrict__ musum,
                                float* __restrict__ sqsum, int N, int F) {
  int t = threadIdx.x;  // F == 256
  float s = 0.f, s2 = 0.f;
  for (int r = blockIdx.x; r < N; r += gridDim.x) {
    float v = x[(size_t)r * F + t];
    s += v;
    s2 += v * v;
  }
  atomicAdd(&musum[t], s);
  atomicAdd(&sqsum[t], s2);
}

__global__ void bn_finalize_kernel(const float* __restrict__ musum, const float* __restrict__ sqsum,
                                   const float* __restrict__ gamma, const float* __restrict__ beta,
                                   float* __restrict__ scale, float* __restrict__ shift, int N) {
  int t = threadIdx.x;
  float m = musum[t] / (float)N;
  float v = sqsum[t] / (float)N - m * m;
  float sc = gamma[t] * rsqrtf(v + 1e-5f);
  scale[t] = sc;
  shift[t] = beta[t] - m * sc;
}

__global__ void bn_apply_bf16_kernel(const float* __restrict__ x, const float* __restrict__ scale,
                                     const float* __restrict__ shift, u16* __restrict__ xin,
                                     int total, int Fmask) {
  int i = blockIdx.x * blockDim.x + threadIdx.x;
  if (i < total) {
    int c = i & Fmask;
    xin[i] = f2bf(x[i] * scale[c] + shift[c]);
  }
}

// ---------------------------------------------------------------------------
// CSR build (dst-indexed)
// ---------------------------------------------------------------------------
__global__ void csr_count_kernel(const int* __restrict__ ei, int E, int N, int* __restrict__ cnt) {
  int e = blockIdx.x * blockDim.x + threadIdx.x;
  int ET = E + N;
  if (e < ET) {
    int d = (e < E) ? ei[E + e] : (e - E);
    atomicAdd(&cnt[d], 1);
  }
}

__global__ void csr_scan_kernel(const int* __restrict__ cnt, int* __restrict__ row_ptr,
                                int* __restrict__ cursor, int N) {
  __shared__ int part[256];
  int t = threadIdx.x;
  int chunk = (N + 255) / 256;
  int lo = t * chunk;
  int hi = min(lo + chunk, N);
  int s = 0;
  for (int i = lo; i < hi; i++) s += cnt[i];
  part[t] = s;
  __syncthreads();
  for (int off = 1; off < 256; off <<= 1) {
    int v = (t >= off) ? part[t - off] : 0;
    __syncthreads();
    part[t] += v;
    __syncthreads();
  }
  int run = (t == 0) ? 0 : part[t - 1];
  for (int i = lo; i < hi; i++) {
    row_ptr[i] = run;
    cursor[i] = run;
    run += cnt[i];
  }
  if (t == 255) row_ptr[N] = part[255];
}

__global__ void csr_fill_kernel(const int* __restrict__ ei, int E, int N,
                                int* __restrict__ cursor, int* __restrict__ csr_src) {
  int e = blockIdx.x * blockDim.x + threadIdx.x;
  int ET = E + N;
  if (e < ET) {
    int s, d;
    if (e < E) { s = ei[e]; d = ei[E + e]; }
    else       { s = e - E; d = s; }
    int pos = atomicAdd(&cursor[d], 1);
    csr_src[pos] = s;
  }
}

// ---------------------------------------------------------------------------
// Weight pre-fragmentation: W fp32 [K][Nc] -> Wt bf16 [Nc][K]
// ---------------------------------------------------------------------------
__global__ void wt_build_all(const float* __restrict__ W1, const float* __restrict__ W2,
                             const float* __restrict__ W3, u16* __restrict__ Wt1,
                             u16* __restrict__ Wt2, u16* __restrict__ Wt3) {
  const int S1 = 256 * 1024, S2 = 1280 * 64, S3 = 64 * 128;
  int idx = blockIdx.x * blockDim.x + threadIdx.x;
  if (idx < S1) {
    int n = idx / 256, k = idx % 256;
    Wt1[idx] = f2bf(W1[(size_t)k * 1024 + n]);
  } else if (idx < S1 + S2) {
    int i = idx - S1;
    int n = i / 1280, k = i % 1280;
    Wt2[i] = f2bf(W2[(size_t)k * 64 + n]);
  } else if (idx < S1 + S2 + S3) {
    int i = idx - S1 - S2;
    int n = i / 64, k = i % 64;
    Wt3[i] = f2bf(W3[(size_t)k * 128 + n]);
  }
}

// ---------------------------------------------------------------------------
// Fold attention vectors into weights: alf[j][k] (bf16, [32][K]) with
// j=2h -> W[:,hC:(h+1)C] @ a_src[h], j=2h+1 -> a_dst. Unused j zeroed.
// ---------------------------------------------------------------------------
__global__ void alfold_build(const float* __restrict__ W1, const float* __restrict__ a1s,
                             const float* __restrict__ a1d, const float* __restrict__ W2,
                             const float* __restrict__ a2s, const float* __restrict__ a2d,
                             const float* __restrict__ W3, const float* __restrict__ a3s,
                             const float* __restrict__ a3d, u16* __restrict__ alf1,
                             u16* __restrict__ alf2, u16* __restrict__ alf3) {
  const int T1 = 32 * 256, T2 = 32 * 1280, T3 = 32 * 64;
  int idx = blockIdx.x * blockDim.x + threadIdx.x;
  if (idx < T1) {  // H=16, C=64
    int jj = idx / 256, k = idx % 256, h = jj >> 1;
    const float* av = (jj & 1) ? a1d : a1s;
    float s = 0.f;
    for (int c = 0; c < 64; c++) s += W1[(size_t)k * 1024 + h * 64 + c] * av[h * 64 + c];
    alf1[idx] = f2bf(s);
  } else if (idx < T1 + T2) {  // H=8, C=8
    int i = idx - T1;
    int jj = i / 1280, k = i % 1280, h = jj >> 1;
    float s = 0.f;
    if (h < 8) {
      const float* av = (jj & 1) ? a2d : a2s;
      for (int c = 0; c < 8; c++) s += W2[(size_t)k * 64 + h * 8 + c] * av[h * 8 + c];
    }
    alf2[i] = f2bf(s);
  } else if (idx < T1 + T2 + T3) {  // H=8, C=16
    int i = idx - T1 - T2;
    int jj = i / 64, k = i % 64, h = jj >> 1;
    float s = 0.f;
    if (h < 8) {
      const float* av = (jj & 1) ? a3d : a3s;
      for (int c = 0; c < 16; c++) s += W3[(size_t)k * 128 + h * 16 + c] * av[h * 16 + c];
    }
    alf3[i] = f2bf(s);
  }
}

// ---------------------------------------------------------------------------
// bf16 MFMA GEMM. A as two bf16 row-major segments (K1 | K-K1), Wt [Nc][K].
// ---------------------------------------------------------------------------
template <int BM, int BN, int FM, int FN>
__global__ __launch_bounds__(256) void mfma_gemm_kernel(
    const u16* __restrict__ A1, const u16* __restrict__ A2, int K1, int K,
    const u16* __restrict__ Wt, u16* __restrict__ Ch, int M, int Nc) {
  constexpr int BK = 32;
  constexpr int CA = (BM * BK) / (256 * 8);
  constexpr int CB = (BN * BK) / (256 * 8);
  static_assert(BM == 2 * FM * 16 && BN == 2 * FN * 16, "wave grid 2x2");
  __shared__ u16 As[BM * BK];
  __shared__ u16 Bs[BN * BK];
  int t = threadIdx.x;
  int m0 = blockIdx.x * BM, n0 = blockIdx.y * BN;
  int r = t & 15;
  int g = (t >> 4) & 3;
  int wid = t >> 6;
  int wm0 = (wid >> 1) * (FM * 16);
  int wn0 = (wid & 1) * (FN * 16);
  int K8 = K >> 3;
  int K2 = K - K1;

  f32x4 acc[FM][FN] = {};
  asm volatile("s_nop 7\n\ts_nop 7" :::);  // VALU acc-init -> MFMA SrcC hazard guard

  for (int k0 = 0; k0 < K; k0 += BK) {
    const u16* Aseg;
    int sA, kl;
    if (k0 < K1) { Aseg = A1; sA = K1; kl = k0; }
    else         { Aseg = A2; sA = K2; kl = k0 - K1; }
    __syncthreads();
#pragma unroll
    for (int i = 0; i < CA; i++) {
      int c = i * 256 + t;
      int m = c >> 2, kb = c & 3;
      *(u32x4*)(As + c * 8) =
          *(const u32x4*)(Aseg + (size_t)(m0 + m) * sA + kl + kb * 8);
    }
#pragma unroll
    for (int i = 0; i < CB; i++) {
      int c = i * 256 + t;
      int nn = c >> 2, kb = c & 3;
      *(u32x4*)(Bs + c * 8) =
          *(const u32x4*)(Wt + ((size_t)(n0 + nn) * K8 + (k0 >> 3) + kb) * 8);
    }
    __syncthreads();
    u32x4 af[FM], bfr[FN];
#pragma unroll
    for (int fi = 0; fi < FM; fi++)
      af[fi] = *(const u32x4*)(As + ((wm0 + fi * 16 + r) * 4 + g) * 8);
#pragma unroll
    for (int fj = 0; fj < FN; fj++)
      bfr[fj] = *(const u32x4*)(Bs + ((wn0 + fj * 16 + r) * 4 + g) * 8);
#pragma unroll
    for (int fi = 0; fi < FM; fi++)
#pragma unroll
      for (int fj = 0; fj < FN; fj++) mfma16(acc[fi][fj], af[fi], bfr[fj]);
  }
  asm volatile("s_nop 7\n\ts_nop 7" :::);  // MFMA -> VALU read hazard guard

#pragma unroll
  for (int fi = 0; fi < FM; fi++) {
#pragma unroll
    for (int fj = 0; fj < FN; fj++) {
#pragma unroll
      for (int v = 0; v < 4; v++) {
        int m = m0 + wm0 + fi * 16 + g * 4 + v;
        int nn = n0 + wn0 + fj * 16 + r;
        if (m < M) Ch[(size_t)m * Nc + nn] = f2bf(acc[fi][fj][v]);
      }
    }
  }
}

// ---------------------------------------------------------------------------
// al GEMM: al = A @ alf^T, BN=32 (FN=1), writes al_s/al_d [M][H] fp32.
// ---------------------------------------------------------------------------
template <int FM, int H>
__global__ __launch_bounds__(256) void al_gemm_kernel(
    const u16* __restrict__ A1, const u16* __restrict__ A2, int K1, int K,
    const u16* __restrict__ alf, float* __restrict__ als, float* __restrict__ ald, int M) {
  constexpr int BM = 2 * FM * 16, BN = 32, BK = 32;
  constexpr int CA = (BM * BK) / (256 * 8);
  __shared__ u16 As[BM * BK];
  __shared__ u16 Bs[BN * BK];
  int t = threadIdx.x;
  int m0 = blockIdx.x * BM;
  int r = t & 15, g = (t >> 4) & 3, wid = t >> 6;
  int wm0 = (wid >> 1) * (FM * 16);
  int wn0 = (wid & 1) * 16;
  int K8 = K >> 3, K2 = K - K1;
  f32x4 acc[FM] = {};
  asm volatile("s_nop 7\n\ts_nop 7" :::);
  for (int k0 = 0; k0 < K; k0 += BK) {
    const u16* Aseg;
    int sA, kl;
    if (k0 < K1) { Aseg = A1; sA = K1; kl = k0; }
    else         { Aseg = A2; sA = K2; kl = k0 - K1; }
    __syncthreads();
#pragma unroll
    for (int i = 0; i < CA; i++) {
      int c = i * 256 + t;
      int mm = c >> 2, kb = c & 3;
      *(u32x4*)(As + c * 8) =
          *(const u32x4*)(Aseg + (size_t)(m0 + mm) * sA + kl + kb * 8);
    }
    if (t < (BN * BK) / 8) {
      int nn = t >> 2, kb = t & 3;
      *(u32x4*)(Bs + t * 8) = *(const u32x4*)(alf + ((size_t)nn * K8 + (k0 >> 3) + kb) * 8);
    }
    __syncthreads();
    u32x4 bfr = *(const u32x4*)(Bs + ((wn0 + r) * 4 + g) * 8);
#pragma unroll
    for (int fi = 0; fi < FM; fi++) {
      u32x4 af = *(const u32x4*)(As + ((wm0 + fi * 16 + r) * 4 + g) * 8);
      mfma16(acc[fi], af, bfr);
    }
  }
  asm volatile("s_nop 7\n\ts_nop 7" :::);
  int nn = wn0 + r;
  if (nn < 2 * H) {
    float* dst = (nn & 1) ? ald : als;
    int hh = nn >> 1;
#pragma unroll
    for (int fi = 0; fi < FM; fi++) {
#pragma unroll
      for (int v = 0; v < 4; v++) {
        int mm = m0 + wm0 + fi * 16 + g * 4 + v;
        if (mm < M) dst[(size_t)mm * H + hh] = acc[fi][v];
      }
    }
  }
}

// ---------------------------------------------------------------------------
// Layer-1 aggregation: 2 waves/node (512 bf16 cols each), unroll-6 pipelined
// gather with clamped index prefetch. head = q*8 + lane/8.
// ---------------------------------------------------------------------------
__global__ __launch_bounds__(256) void gat_agg1_wave(
    const u16* __restrict__ xwh, const float* __restrict__ alsrc,
    const float* __restrict__ aldst, const int* __restrict__ row_ptr,
    const int* __restrict__ csr_src, const float* __restrict__ bias,
    const float* __restrict__ slope_p, u16* __restrict__ out, int N) {
  constexpr int U = 6;
  int wid = blockIdx.x * 4 + (threadIdx.x >> 6);
  int n = wid >> 1, q = wid & 1;
  if (n >= N) return;
  int lane = threadIdx.x & 63;
  int head = q * 8 + (lane >> 3), g = lane & 7;
  float ad = aldst[(size_t)n * 16 + head];
  int start = row_ptr[n];
  int end = row_ptr[n + 1];
  int deg = end - start;
  int endm1 = end - 1;

  // phase A: online softmax stats (8 lanes per head)
  float m = -1e30f, s = 0.f;
  for (int j = g; j < deg; j += 8) {
    int sj = csr_src[start + j];
    float e = lrelu(alsrc[(size_t)sj * 16 + head] + ad);
    float mn = fmaxf(m, e);
    s = s * __expf(m - mn) + __expf(e - mn);
    m = mn;
  }
#pragma unroll
  for (int st = 1; st <= 4; st <<= 1) {
    float m2 = __shfl_xor(m, st);
    float s2 = __shfl_xor(s, st);
    float mn = fmaxf(m, m2);
    s = s * __expf(m - mn) + s2 * __expf(m2 - mn);
    m = mn;
  }
  float rr = 1.f / (s + 1e-16f);

  // phase B: pipelined weighted gather
  float acc[8] = {};
  const u16* base = xwh + (size_t)q * 512 + (size_t)lane * 8;

  auto fma8 = [&](const u32x4& v, float w) {
#pragma unroll
    for (int i = 0; i < 4; i++) {
      u32 u = v[i];
      acc[2 * i] = fmaf(w, bf2f(u & 0xffffu), acc[2 * i]);
      acc[2 * i + 1] = fmaf(w, bf2f(u >> 16), acc[2 * i + 1]);
    }
  };

  int c[U];
#pragma unroll
  for (int i = 0; i < U; i++) c[i] = csr_src[min(start + i, endm1)];
  int j = 0;
  for (; j + U <= deg; j += U) {
    u32x4 v[U];
    float a[U];
#pragma unroll
    for (int i = 0; i < U; i++) v[i] = *(const u32x4*)(base + (size_t)c[i] * 1024);
#pragma unroll
    for (int i = 0; i < U; i++) a[i] = alsrc[(size_t)c[i] * 16 + head];
#pragma unroll
    for (int i = 0; i < U; i++) c[i] = csr_src[min(start + j + U + i, endm1)];
#pragma unroll
    for (int i = 0; i < U; i++) {
      float w = __expf(lrelu(a[i] + ad) - m) * rr;
      fma8(v[i], w);
    }
  }
  for (int i = 0; j < deg; j++, i++) {
    u32x4 v = *(const u32x4*)(base + (size_t)c[i] * 1024);
    float a = alsrc[(size_t)c[i] * 16 + head];
    float w = __expf(lrelu(a + ad) - m) * rr;
    fma8(v, w);
  }

  // epilogue: bias + PReLU -> bf16
  float p = slope_p[0];
  u32 ow[4];
#pragma unroll
  for (int i = 0; i < 4; i++) {
    int cc = q * 512 + lane * 8 + 2 * i;
    float v0 = acc[2 * i] + bias[cc];
    float v1 = acc[2 * i + 1] + bias[cc + 1];
    v0 = (v0 >= 0.f) ? v0 : p * v0;
    v1 = (v1 >= 0.f) ? v1 : p * v1;
    ow[i] = (u32)f2bf(v0) | ((u32)f2bf(v1) << 16);
  }
  *(u32x4*)((u32*)(out + (size_t)n * 1024 + q * 512) + lane * 4) = *(u32x4*)ow;
}

// ---------------------------------------------------------------------------
// Layer-2 aggregation, one wave per node, unroll-8 pipelined. bf16 rows 128B.
// ---------------------------------------------------------------------------
__global__ __launch_bounds__(256) void gat_agg2_wave(
    const u16* __restrict__ xwh, const float* __restrict__ alsrc,
    const float* __restrict__ aldst, const int* __restrict__ row_ptr,
    const int* __restrict__ csr_src, const float* __restrict__ bias,
    const float* __restrict__ slope_p, u16* __restrict__ out, int N) {
  constexpr int U = 8;
  int n = blockIdx.x * 4 + (threadIdx.x >> 6);
  if (n >= N) return;
  int lane = threadIdx.x & 63;
  int head = lane >> 3, g = lane & 7;
  float ad = aldst[(size_t)n * 8 + head];
  int start = row_ptr[n];
  int end = row_ptr[n + 1];
  int deg = end - start;
  int endm1 = end - 1;

  float m = -1e30f, s = 0.f;
  for (int j = g; j < deg; j += 8) {
    int sj = csr_src[start + j];
    float e = lrelu(alsrc[(size_t)sj * 8 + head] + ad);
    float mn = fmaxf(m, e);
    s = s * __expf(m - mn) + __expf(e - mn);
    m = mn;
  }
#pragma unroll
  for (int st = 1; st <= 4; st <<= 1) {
    float m2 = __shfl_xor(m, st);
    float s2 = __shfl_xor(s, st);
    float mn = fmaxf(m, m2);
    s = s * __expf(m - mn) + s2 * __expf(m2 - mn);
    m = mn;
  }
  float rr = 1.f / (s + 1e-16f);

  float acc = 0.f;
  int c[U];
#pragma unroll
  for (int i = 0; i < U; i++) c[i] = csr_src[min(start + i, endm1)];
  int j = 0;
  for (; j + U <= deg; j += U) {
    u16 v[U];
    float a[U];
#pragma unroll
    for (int i = 0; i < U; i++) v[i] = xwh[(size_t)c[i] * 64 + lane];
#pragma unroll
    for (int i = 0; i < U; i++) a[i] = alsrc[(size_t)c[i] * 8 + head];
#pragma unroll
    for (int i = 0; i < U; i++) c[i] = csr_src[min(start + j + U + i, endm1)];
#pragma unroll
    for (int i = 0; i < U; i++) {
      float w = __expf(lrelu(a[i] + ad) - m) * rr;
      acc = fmaf(w, bf2f(v[i]), acc);
    }
  }
  for (int i = 0; j < deg; j++, i++) {
    float v = bf2f(xwh[(size_t)c[i] * 64 + lane]);
    float w = __expf(lrelu(alsrc[(size_t)c[i] * 8 + head] + ad) - m) * rr;
    acc = fmaf(w, v, acc);
  }

  float p = slope_p[0];
  float v = acc + bias[lane];
  out[(size_t)n * 64 + lane] = f2bf((v >= 0.f) ? v : p * v);
}

// ---------------------------------------------------------------------------
// Layer-3 aggregation, one wave per node, unroll-8 pipelined. bf16 rows 256B.
// Mean over heads + log_softmax.
// ---------------------------------------------------------------------------
__global__ __launch_bounds__(256) void gat_agg3_wave(
    const u16* __restrict__ xwh, const float* __restrict__ alsrc,
    const float* __restrict__ aldst, const int* __restrict__ row_ptr,
    const int* __restrict__ csr_src, const float* __restrict__ bias,
    float* __restrict__ out, int N) {
  constexpr int U = 8;
  int n = blockIdx.x * 4 + (threadIdx.x >> 6);
  if (n >= N) return;
  int lane = threadIdx.x & 63;
  int head = lane >> 3, g = lane & 7;
  float ad = aldst[(size_t)n * 8 + head];
  int start = row_ptr[n];
  int end = row_ptr[n + 1];
  int deg = end - start;
  int endm1 = end - 1;

  float m = -1e30f, s = 0.f;
  for (int j = g; j < deg; j += 8) {
    int sj = csr_src[start + j];
    float e = lrelu(alsrc[(size_t)sj * 8 + head] + ad);
    float mn = fmaxf(m, e);
    s = s * __expf(m - mn) + __expf(e - mn);
    m = mn;
  }
#pragma unroll
  for (int st = 1; st <= 4; st <<= 1) {
    float m2 = __shfl_xor(m, st);
    float s2 = __shfl_xor(s, st);
    float mn = fmaxf(m, m2);
    s = s * __expf(m - mn) + s2 * __expf(m2 - mn);
    m = mn;
  }
  float rr = 1.f / (s + 1e-16f);

  float a0 = 0.f, a1 = 0.f;
  int c[U];
#pragma unroll
  for (int i = 0; i < U; i++) c[i] = csr_src[min(start + i, endm1)];
  int j = 0;
  for (; j + U <= deg; j += U) {
    u32 v[U];
    float a[U];
#pragma unroll
    for (int i = 0; i < U; i++) v[i] = *(const u32*)(xwh + (size_t)c[i] * 128 + lane * 2);
#pragma unroll
    for (int i = 0; i < U; i++) a[i] = alsrc[(size_t)c[i] * 8 + head];
#pragma unroll
    for (int i = 0; i < U; i++) c[i] = csr_src[min(start + j + U + i, endm1)];
#pragma unroll
    for (int i = 0; i < U; i++) {
      float w = __expf(lrelu(a[i] + ad) - m) * rr;
      a0 = fmaf(w, bf2f(v[i] & 0xffffu), a0);
      a1 = fmaf(w, bf2f(v[i] >> 16), a1);
    }
  }
  for (int i = 0; j < deg; j++, i++) {
    u32 v = *(const u32*)(xwh + (size_t)c[i] * 128 + lane * 2);
    float w = __expf(lrelu(alsrc[(size_t)c[i] * 8 + head] + ad) - m) * rr;
    a0 = fmaf(w, bf2f(v & 0xffffu), a0);
    a1 = fmaf(w, bf2f(v >> 16), a1);
  }

  // sum across heads (bits 3..5 of lane select the head)
#pragma unroll
  for (int st = 8; st <= 32; st <<= 1) {
    a0 += __shfl_xor(a0, st);
    a1 += __shfl_xor(a1, st);
  }
  int c0 = (2 * lane) & 15, c1 = (2 * lane + 1) & 15;
  float v0 = a0 * 0.125f + bias[c0];
  float v1 = a1 * 0.125f + bias[c1];
  float mx = fmaxf(v0, v1);
#pragma unroll
  for (int st = 1; st <= 4; st <<= 1) mx = fmaxf(mx, __shfl_xor(mx, st));
  float se = __expf(v0 - mx) + __expf(v1 - mx);
#pragma unroll
  for (int st = 1; st <= 4; st <<= 1) se += __shfl_xor(se, st);
  float lse = mx + logf(se);
  if (lane < 8) {
    float2 o = make_float2(v0 - lse, v1 - lse);
    *((float2*)(out + (size_t)n * 16) + lane) = o;
  }
}

// ---------------------------------------------------------------------------
extern "C" void kernel_launch(void* const* d_in, const int* in_sizes, int n_in,
                              void* d_out, int out_size, void* d_ws, size_t ws_size,
                              hipStream_t stream) {
  const float* x        = (const float*)d_in[0];
  const int*   ei       = (const int*)d_in[1];
  const float* bn_gamma = (const float*)d_in[2];
  const float* bn_beta  = (const float*)d_in[3];
  const float* W1       = (const float*)d_in[4];
  const float* a1s      = (const float*)d_in[5];
  const float* a1d      = (const float*)d_in[6];
  const float* b1       = (const float*)d_in[7];
  const float* p1       = (const float*)d_in[8];
  const float* W2       = (const float*)d_in[9];
  const float* a2s      = (const float*)d_in[10];
  const float* a2d      = (const float*)d_in[11];
  const float* b2       = (const float*)d_in[12];
  const float* p2       = (const float*)d_in[13];
  const float* W3       = (const float*)d_in[14];
  const float* a3s      = (const float*)d_in[15];
  const float* a3d      = (const float*)d_in[16];
  const float* b3       = (const float*)d_in[17];
  float* out = (float*)d_out;

  const int F  = in_sizes[2];       // 256
  const int N  = in_sizes[0] / F;   // 20000
  const int E  = in_sizes[1] / 2;   // 320000
  const int ET = E + N;
  const int MP = ((N + 127) / 128) * 128;  // MFMA row padding

  size_t off = 0;
  auto alloc = [&](size_t bytes) -> char* {
    char* r = (char*)d_ws + off;
    off += (bytes + 255) & ~(size_t)255;
    return r;
  };
  float* musum   = (float*)alloc(F * 4);
  float* sqsum   = (float*)alloc(F * 4);
  float* scale   = (float*)alloc(F * 4);
  float* shift   = (float*)alloc(F * 4);
  int*   row_ptr = (int*)alloc((size_t)(N + 1) * 4);
  int*   cursor  = (int*)alloc((size_t)N * 4);
  int*   csr_src = (int*)alloc((size_t)ET * 4);
  float* al_s    = (float*)alloc((size_t)N * 16 * 4);
  float* al_d    = (float*)alloc((size_t)N * 16 * 4);
  u16*   Wt1     = (u16*)alloc((size_t)256 * 1024 * 2);
  u16*   Wt2     = (u16*)alloc((size_t)1280 * 64 * 2);
  u16*   Wt3     = (u16*)alloc((size_t)64 * 128 * 2);
  u16*   alf1    = (u16*)alloc((size_t)32 * 256 * 2);
  u16*   alf2    = (u16*)alloc((size_t)32 * 1280 * 2);
  u16*   alf3    = (u16*)alloc((size_t)32 * 64 * 2);
  u16*   x_in_h  = (u16*)alloc((size_t)MP * 256 * 2);
  u16*   xw1h    = (u16*)alloc((size_t)MP * 1024 * 2);
  u16*   h1      = (u16*)alloc((size_t)MP * 1024 * 2);
  u16*   xw2h    = (u16*)alloc((size_t)MP * 64 * 2);
  u16*   h2h     = (u16*)alloc((size_t)MP * 64 * 2);
  u16*   xw3h    = (u16*)alloc((size_t)MP * 128 * 2);

  // ---- BatchNorm ----
  hipMemsetAsync(musum, 0, (size_t)2 * F * 4, stream);
  bn_stats_kernel<<<256, 256, 0, stream>>>(x, musum, sqsum, N, F);
  bn_finalize_kernel<<<1, F, 0, stream>>>(musum, sqsum, bn_gamma, bn_beta, scale, shift, N);
  int totalXF = N * F;
  bn_apply_bf16_kernel<<<(totalXF + 255) / 256, 256, 0, stream>>>(x, scale, shift, x_in_h,
                                                                  totalXF, F - 1);

  // ---- CSR by dst ----
  hipMemsetAsync(cursor, 0, (size_t)N * 4, stream);
  csr_count_kernel<<<(ET + 255) / 256, 256, 0, stream>>>(ei, E, N, cursor);
  csr_scan_kernel<<<1, 256, 0, stream>>>(cursor, row_ptr, cursor, N);
  csr_fill_kernel<<<(ET + 255) / 256, 256, 0, stream>>>(ei, E, N, cursor, csr_src);

  // ---- weight prep ----
  {
    int total = 256 * 1024 + 1280 * 64 + 64 * 128;
    wt_build_all<<<(total + 255) / 256, 256, 0, stream>>>(W1, W2, W3, Wt1, Wt2, Wt3);
    int tot2 = 32 * 256 + 32 * 1280 + 32 * 64;
    alfold_build<<<(tot2 + 255) / 256, 256, 0, stream>>>(W1, a1s, a1d, W2, a2s, a2d, W3, a3s, a3d,
                                                         alf1, alf2, alf3);
  }

  int nblk = (N + 3) / 4;

  // ---- Layer 1: H=16, C=64 ----
  {
    dim3 grid(MP / 128, 1024 / 128);
    mfma_gemm_kernel<128, 128, 4, 4><<<grid, 256, 0, stream>>>(
        x_in_h, x_in_h, 256, 256, Wt1, xw1h, N, 1024);
    al_gemm_kernel<4, 16><<<MP / 128, 256, 0, stream>>>(x_in_h, x_in_h, 256, 256, alf1, al_s, al_d,
                                                        N);
    gat_agg1_wave<<<(2 * N + 3) / 4, 256, 0, stream>>>(xw1h, al_s, al_d, row_ptr, csr_src, b1, p1,
                                                       h1, N);
  }

  // ---- Layer 2: concat([x_in,h1]), H=8, C=8 ----
  {
    dim3 grid((N + 63) / 64, 1);
    mfma_gemm_kernel<64, 64, 2, 2><<<grid, 256, 0, stream>>>(
        x_in_h, h1, 256, 1280, Wt2, xw2h, N, 64);
    al_gemm_kernel<4, 8><<<MP / 128, 256, 0, stream>>>(x_in_h, h1, 256, 1280, alf2, al_s, al_d, N);
    gat_agg2_wave<<<nblk, 256, 0, stream>>>(xw2h, al_s, al_d, row_ptr, csr_src, b2, p2, h2h, N);
  }

  // ---- Layer 3: H=8, C=16, mean + log_softmax ----
  {
    dim3 grid((N + 63) / 64, 128 / 64);
    mfma_gemm_kernel<64, 64, 2, 2><<<grid, 256, 0, stream>>>(
        h2h, h2h, 64, 64, Wt3, xw3h, N, 128);
    al_gemm_kernel<4, 8><<<MP / 128, 256, 0, stream>>>(h2h, h2h, 64, 64, alf3, al_s, al_d, N);
    gat_agg3_wave<<<nblk, 256, 0, stream>>>(xw3h, al_s, al_d, row_ptr, csr_src, b3, out, N);
  }
}

// Round 6
// 343.674 us; speedup vs baseline: 2.0921x; 1.0720x over previous
//
#include <hip/hip_runtime.h>
#include <math.h>

typedef unsigned int u32;
typedef unsigned short u16;
typedef u32 u32x4 __attribute__((ext_vector_type(4)));
typedef float f32x4 __attribute__((ext_vector_type(4)));

__device__ __forceinline__ u16 f2bf(float f) {
  u32 u = __builtin_bit_cast(u32, f);
  return (u16)((u + 0x7FFFu + ((u >> 16) & 1u)) >> 16);
}
__device__ __forceinline__ float bf2f(u32 lo16) {
  return __builtin_bit_cast(float, lo16 << 16);
}
__device__ __forceinline__ void mfma16(f32x4& c, const u32x4& a, const u32x4& b) {
  asm volatile("v_mfma_f32_16x16x32_bf16 %0, %1, %2, %0" : "+v"(c) : "v"(a), "v"(b));
}
__device__ __forceinline__ float lrelu(float e) { return fmaxf(e, 0.2f * e); }

// ---------------------------------------------------------------------------
// BatchNorm
// ---------------------------------------------------------------------------
__global__ void bn_stats_kernel(const float* __restrict__ x, float* __restrict__ musum,
                                float* __restrict__ sqsum, int N, int F) {
  int t = threadIdx.x;  // F == 256
  float s = 0.f, s2 = 0.f;
  for (int r = blockIdx.x; r < N; r += gridDim.x) {
    float v = x[(size_t)r * F + t];
    s += v;
    s2 += v * v;
  }
  atomicAdd(&musum[t], s);
  atomicAdd(&sqsum[t], s2);
}

__global__ void bn_finalize_kernel(const float* __restrict__ musum, const float* __restrict__ sqsum,
                                   const float* __restrict__ gamma, const float* __restrict__ beta,
                                   float* __restrict__ scale, float* __restrict__ shift, int N) {
  int t = threadIdx.x;
  float m = musum[t] / (float)N;
  float v = sqsum[t] / (float)N - m * m;
  float sc = gamma[t] * rsqrtf(v + 1e-5f);
  scale[t] = sc;
  shift[t] = beta[t] - m * sc;
}

__global__ void bn_apply_bf16_kernel(const float* __restrict__ x, const float* __restrict__ scale,
                                     const float* __restrict__ shift, u16* __restrict__ xin,
                                     int total, int Fmask) {
  int i = blockIdx.x * blockDim.x + threadIdx.x;
  if (i < total) {
    int c = i & Fmask;
    xin[i] = f2bf(x[i] * scale[c] + shift[c]);
  }
}

// ---------------------------------------------------------------------------
// CSR build (dst-indexed)
// ---------------------------------------------------------------------------
__global__ void csr_count_kernel(const int* __restrict__ ei, int E, int N, int* __restrict__ cnt) {
  int e = blockIdx.x * blockDim.x + threadIdx.x;
  int ET = E + N;
  if (e < ET) {
    int d = (e < E) ? ei[E + e] : (e - E);
    atomicAdd(&cnt[d], 1);
  }
}

__global__ __launch_bounds__(1024) void csr_scan_kernel(const int* __restrict__ cnt,
                                                        int* __restrict__ row_ptr,
                                                        int* __restrict__ cursor, int N) {
  __shared__ int part[1024];
  int t = threadIdx.x;
  int chunk = (N + 1023) / 1024;
  int lo = t * chunk;
  int hi = min(lo + chunk, N);
  int s = 0;
  for (int i = lo; i < hi; i++) s += cnt[i];
  part[t] = s;
  __syncthreads();
  for (int off = 1; off < 1024; off <<= 1) {
    int v = (t >= off) ? part[t - off] : 0;
    __syncthreads();
    part[t] += v;
    __syncthreads();
  }
  int run = (t == 0) ? 0 : part[t - 1];
  for (int i = lo; i < hi; i++) {
    row_ptr[i] = run;
    cursor[i] = run;
    run += cnt[i];
  }
  if (t == 1023) row_ptr[N] = part[1023];
}

__global__ void csr_fill_kernel(const int* __restrict__ ei, int E, int N,
                                int* __restrict__ cursor, int* __restrict__ csr_src) {
  int e = blockIdx.x * blockDim.x + threadIdx.x;
  int ET = E + N;
  if (e < ET) {
    int s, d;
    if (e < E) { s = ei[e]; d = ei[E + e]; }
    else       { s = e - E; d = s; }
    int pos = atomicAdd(&cursor[d], 1);
    csr_src[pos] = s;
  }
}

// ---------------------------------------------------------------------------
// Weight pre-fragmentation into EXTENDED Wt arrays (bf16, [Nc_tot][K]):
//   Wt1ext [1152][256]: rows 0..1023 = W1^T, 1024..1055 = al-fold, rest 0
//   Wt2ext [  96][1280]: rows 0..63  = W2^T,   64..79   = al-fold, rest 0
//   Wt3ext [ 160][  64]: rows 0..127 = W3^T,  128..143  = al-fold, rest 0
// ---------------------------------------------------------------------------
__global__ void wt_build_all(const float* __restrict__ W1, const float* __restrict__ W2,
                             const float* __restrict__ W3, u16* __restrict__ Wt1,
                             u16* __restrict__ Wt2, u16* __restrict__ Wt3) {
  const int S1 = 1024 * 256, S2 = 64 * 1280, S3 = 128 * 64;
  const int P1 = 96 * 256, P2 = 32 * 1280, P3 = 32 * 64;  // pad+al rows zero-init
  int idx = blockIdx.x * blockDim.x + threadIdx.x;
  if (idx < S1) {
    int n = idx / 256, k = idx % 256;
    Wt1[idx] = f2bf(W1[(size_t)k * 1024 + n]);
  } else if (idx < S1 + S2) {
    int i = idx - S1;
    int n = i / 1280, k = i % 1280;
    Wt2[i] = f2bf(W2[(size_t)k * 64 + n]);
  } else if (idx < S1 + S2 + S3) {
    int i = idx - S1 - S2;
    int n = i / 64, k = i % 64;
    Wt3[i] = f2bf(W3[(size_t)k * 128 + n]);
  } else if (idx < S1 + S2 + S3 + P1) {
    Wt1[S1 + (idx - S1 - S2 - S3)] = 0;
  } else if (idx < S1 + S2 + S3 + P1 + P2) {
    Wt2[S2 + (idx - S1 - S2 - S3 - P1)] = 0;
  } else if (idx < S1 + S2 + S3 + P1 + P2 + P3) {
    Wt3[S3 + (idx - S1 - S2 - S3 - P1 - P2)] = 0;
  }
}

// Fold attention vectors: row NcH + 2h (+1) of Wtext = W[:,hC:(h+1)C] @ a_{src,dst}[h]
__global__ void alfold_build(const float* __restrict__ W1, const float* __restrict__ a1s,
                             const float* __restrict__ a1d, const float* __restrict__ W2,
                             const float* __restrict__ a2s, const float* __restrict__ a2d,
                             const float* __restrict__ W3, const float* __restrict__ a3s,
                             const float* __restrict__ a3d, u16* __restrict__ Wt1,
                             u16* __restrict__ Wt2, u16* __restrict__ Wt3) {
  const int T1 = 32 * 256, T2 = 16 * 1280, T3 = 16 * 64;
  int idx = blockIdx.x * blockDim.x + threadIdx.x;
  if (idx < T1) {  // H=16, C=64
    int jj = idx / 256, k = idx % 256, h = jj >> 1;
    const float* av = (jj & 1) ? a1d : a1s;
    float s = 0.f;
    for (int c = 0; c < 64; c++) s += W1[(size_t)k * 1024 + h * 64 + c] * av[h * 64 + c];
    Wt1[(size_t)(1024 + jj) * 256 + k] = f2bf(s);
  } else if (idx < T1 + T2) {  // H=8, C=8
    int i = idx - T1;
    int jj = i / 1280, k = i % 1280, h = jj >> 1;
    const float* av = (jj & 1) ? a2d : a2s;
    float s = 0.f;
    for (int c = 0; c < 8; c++) s += W2[(size_t)k * 64 + h * 8 + c] * av[h * 8 + c];
    Wt2[(size_t)(64 + jj) * 1280 + k] = f2bf(s);
  } else if (idx < T1 + T2 + T3) {  // H=8, C=16
    int i = idx - T1 - T2;
    int jj = i / 64, k = i % 64, h = jj >> 1;
    const float* av = (jj & 1) ? a3d : a3s;
    float s = 0.f;
    for (int c = 0; c < 16; c++) s += W3[(size_t)k * 128 + h * 16 + c] * av[h * 16 + c];
    Wt3[(size_t)(128 + jj) * 64 + k] = f2bf(s);
  }
}

// ---------------------------------------------------------------------------
// bf16 MFMA GEMM with fused al epilogue. A = two bf16 segments (K1 | K-K1),
// Wt [Nc_tot][K]. Cols < NcH -> bf16 Ch; cols NcH..NcH+ALN-1 -> fp32 al_s/al_d.
// ---------------------------------------------------------------------------
template <int BM, int BN, int FM, int FN>
__global__ __launch_bounds__(256) void mfma_gemm_al(
    const u16* __restrict__ A1, const u16* __restrict__ A2, int K1, int K,
    const u16* __restrict__ Wt, u16* __restrict__ Ch, int NcH,
    float* __restrict__ als, float* __restrict__ ald, int ALN, int M) {
  constexpr int BK = 32;
  constexpr int ACH = (BM * BK) / 8;  // 16B chunks in A tile
  constexpr int BCH = (BN * BK) / 8;
  static_assert(BM == 2 * FM * 16 && BN == 2 * FN * 16, "wave grid 2x2");
  __shared__ u16 As[BM * BK];
  __shared__ u16 Bs[BN * BK];
  int t = threadIdx.x;
  int m0 = blockIdx.x * BM, n0 = blockIdx.y * BN;
  int r = t & 15;
  int g = (t >> 4) & 3;
  int wid = t >> 6;
  int wm0 = (wid >> 1) * (FM * 16);
  int wn0 = (wid & 1) * (FN * 16);
  int K8 = K >> 3;
  int K2 = K - K1;

  f32x4 acc[FM][FN] = {};
  asm volatile("s_nop 7\n\ts_nop 7" :::);  // VALU acc-init -> MFMA SrcC hazard guard

  for (int k0 = 0; k0 < K; k0 += BK) {
    const u16* Aseg;
    int sA, kl;
    if (k0 < K1) { Aseg = A1; sA = K1; kl = k0; }
    else         { Aseg = A2; sA = K2; kl = k0 - K1; }
    __syncthreads();
#pragma unroll
    for (int i = 0; i < (ACH + 255) / 256; i++) {
      int c = i * 256 + t;
      if (ACH % 256 == 0 || c < ACH) {
        int m = c >> 2, kb = c & 3;
        *(u32x4*)(As + c * 8) =
            *(const u32x4*)(Aseg + (size_t)(m0 + m) * sA + kl + kb * 8);
      }
    }
#pragma unroll
    for (int i = 0; i < (BCH + 255) / 256; i++) {
      int c = i * 256 + t;
      if (BCH % 256 == 0 || c < BCH) {
        int nn = c >> 2, kb = c & 3;
        *(u32x4*)(Bs + c * 8) =
            *(const u32x4*)(Wt + ((size_t)(n0 + nn) * K8 + (k0 >> 3) + kb) * 8);
      }
    }
    __syncthreads();
    u32x4 af[FM], bfr[FN];
#pragma unroll
    for (int fi = 0; fi < FM; fi++)
      af[fi] = *(const u32x4*)(As + ((wm0 + fi * 16 + r) * 4 + g) * 8);
#pragma unroll
    for (int fj = 0; fj < FN; fj++)
      bfr[fj] = *(const u32x4*)(Bs + ((wn0 + fj * 16 + r) * 4 + g) * 8);
#pragma unroll
    for (int fi = 0; fi < FM; fi++)
#pragma unroll
      for (int fj = 0; fj < FN; fj++) mfma16(acc[fi][fj], af[fi], bfr[fj]);
  }
  asm volatile("s_nop 7\n\ts_nop 7" :::);  // MFMA -> VALU read hazard guard

#pragma unroll
  for (int fi = 0; fi < FM; fi++) {
#pragma unroll
    for (int fj = 0; fj < FN; fj++) {
#pragma unroll
      for (int v = 0; v < 4; v++) {
        int m = m0 + wm0 + fi * 16 + g * 4 + v;
        int nn = n0 + wn0 + fj * 16 + r;
        if (m < M) {
          float val = acc[fi][fj][v];
          if (nn < NcH) {
            Ch[(size_t)m * NcH + nn] = f2bf(val);
          } else {
            int j = nn - NcH;
            if (j < ALN) ((j & 1) ? ald : als)[(size_t)m * (ALN >> 1) + (j >> 1)] = val;
          }
        }
      }
    }
  }
}

// ---------------------------------------------------------------------------
// Layer-1 aggregation: 2 waves/node (512 bf16 cols each), unroll-6 pipelined
// gather with clamped index prefetch. head = q*8 + lane/8.
// ---------------------------------------------------------------------------
__global__ __launch_bounds__(256) void gat_agg1_wave(
    const u16* __restrict__ xwh, const float* __restrict__ alsrc,
    const float* __restrict__ aldst, const int* __restrict__ row_ptr,
    const int* __restrict__ csr_src, const float* __restrict__ bias,
    const float* __restrict__ slope_p, u16* __restrict__ out, int N) {
  constexpr int U = 6;
  int wid = blockIdx.x * 4 + (threadIdx.x >> 6);
  int n = wid >> 1, q = wid & 1;
  if (n >= N) return;
  int lane = threadIdx.x & 63;
  int head = q * 8 + (lane >> 3), g = lane & 7;
  float ad = aldst[(size_t)n * 16 + head];
  int start = row_ptr[n];
  int end = row_ptr[n + 1];
  int deg = end - start;
  int endm1 = end - 1;

  float m = -1e30f, s = 0.f;
  for (int j = g; j < deg; j += 8) {
    int sj = csr_src[start + j];
    float e = lrelu(alsrc[(size_t)sj * 16 + head] + ad);
    float mn = fmaxf(m, e);
    s = s * __expf(m - mn) + __expf(e - mn);
    m = mn;
  }
#pragma unroll
  for (int st = 1; st <= 4; st <<= 1) {
    float m2 = __shfl_xor(m, st);
    float s2 = __shfl_xor(s, st);
    float mn = fmaxf(m, m2);
    s = s * __expf(m - mn) + s2 * __expf(m2 - mn);
    m = mn;
  }
  float rr = 1.f / (s + 1e-16f);

  float acc[8] = {};
  const u16* base = xwh + (size_t)q * 512 + (size_t)lane * 8;

  auto fma8 = [&](const u32x4& v, float w) {
#pragma unroll
    for (int i = 0; i < 4; i++) {
      u32 u = v[i];
      acc[2 * i] = fmaf(w, bf2f(u & 0xffffu), acc[2 * i]);
      acc[2 * i + 1] = fmaf(w, bf2f(u >> 16), acc[2 * i + 1]);
    }
  };

  int c[U];
#pragma unroll
  for (int i = 0; i < U; i++) c[i] = csr_src[min(start + i, endm1)];
  int j = 0;
  for (; j + U <= deg; j += U) {
    u32x4 v[U];
    float a[U];
#pragma unroll
    for (int i = 0; i < U; i++) v[i] = *(const u32x4*)(base + (size_t)c[i] * 1024);
#pragma unroll
    for (int i = 0; i < U; i++) a[i] = alsrc[(size_t)c[i] * 16 + head];
#pragma unroll
    for (int i = 0; i < U; i++) c[i] = csr_src[min(start + j + U + i, endm1)];
#pragma unroll
    for (int i = 0; i < U; i++) {
      float w = __expf(lrelu(a[i] + ad) - m) * rr;
      fma8(v[i], w);
    }
  }
  for (int i = 0; j < deg; j++, i++) {
    u32x4 v = *(const u32x4*)(base + (size_t)c[i] * 1024);
    float a = alsrc[(size_t)c[i] * 16 + head];
    float w = __expf(lrelu(a + ad) - m) * rr;
    fma8(v, w);
  }

  float p = slope_p[0];
  u32 ow[4];
#pragma unroll
  for (int i = 0; i < 4; i++) {
    int cc = q * 512 + lane * 8 + 2 * i;
    float v0 = acc[2 * i] + bias[cc];
    float v1 = acc[2 * i + 1] + bias[cc + 1];
    v0 = (v0 >= 0.f) ? v0 : p * v0;
    v1 = (v1 >= 0.f) ? v1 : p * v1;
    ow[i] = (u32)f2bf(v0) | ((u32)f2bf(v1) << 16);
  }
  *(u32x4*)((u32*)(out + (size_t)n * 1024 + q * 512) + lane * 4) = *(u32x4*)ow;
}

// ---------------------------------------------------------------------------
// Layer-2 aggregation, one wave per node, unroll-8 pipelined. bf16 rows 128B.
// ---------------------------------------------------------------------------
__global__ __launch_bounds__(256) void gat_agg2_wave(
    const u16* __restrict__ xwh, const float* __restrict__ alsrc,
    const float* __restrict__ aldst, const int* __restrict__ row_ptr,
    const int* __restrict__ csr_src, const float* __restrict__ bias,
    const float* __restrict__ slope_p, u16* __restrict__ out, int N) {
  constexpr int U = 8;
  int n = blockIdx.x * 4 + (threadIdx.x >> 6);
  if (n >= N) return;
  int lane = threadIdx.x & 63;
  int head = lane >> 3, g = lane & 7;
  float ad = aldst[(size_t)n * 8 + head];
  int start = row_ptr[n];
  int end = row_ptr[n + 1];
  int deg = end - start;
  int endm1 = end - 1;

  float m = -1e30f, s = 0.f;
  for (int j = g; j < deg; j += 8) {
    int sj = csr_src[start + j];
    float e = lrelu(alsrc[(size_t)sj * 8 + head] + ad);
    float mn = fmaxf(m, e);
    s = s * __expf(m - mn) + __expf(e - mn);
    m = mn;
  }
#pragma unroll
  for (int st = 1; st <= 4; st <<= 1) {
    float m2 = __shfl_xor(m, st);
    float s2 = __shfl_xor(s, st);
    float mn = fmaxf(m, m2);
    s = s * __expf(m - mn) + s2 * __expf(m2 - mn);
    m = mn;
  }
  float rr = 1.f / (s + 1e-16f);

  float acc = 0.f;
  int c[U];
#pragma unroll
  for (int i = 0; i < U; i++) c[i] = csr_src[min(start + i, endm1)];
  int j = 0;
  for (; j + U <= deg; j += U) {
    u16 v[U];
    float a[U];
#pragma unroll
    for (int i = 0; i < U; i++) v[i] = xwh[(size_t)c[i] * 64 + lane];
#pragma unroll
    for (int i = 0; i < U; i++) a[i] = alsrc[(size_t)c[i] * 8 + head];
#pragma unroll
    for (int i = 0; i < U; i++) c[i] = csr_src[min(start + j + U + i, endm1)];
#pragma unroll
    for (int i = 0; i < U; i++) {
      float w = __expf(lrelu(a[i] + ad) - m) * rr;
      acc = fmaf(w, bf2f(v[i]), acc);
    }
  }
  for (int i = 0; j < deg; j++, i++) {
    float v = bf2f(xwh[(size_t)c[i] * 64 + lane]);
    float w = __expf(lrelu(alsrc[(size_t)c[i] * 8 + head] + ad) - m) * rr;
    acc = fmaf(w, v, acc);
  }

  float p = slope_p[0];
  float v = acc + bias[lane];
  out[(size_t)n * 64 + lane] = f2bf((v >= 0.f) ? v : p * v);
}

// ---------------------------------------------------------------------------
// Layer-3 aggregation, one wave per node, unroll-8 pipelined. bf16 rows 256B.
// Mean over heads + log_softmax.
// ---------------------------------------------------------------------------
__global__ __launch_bounds__(256) void gat_agg3_wave(
    const u16* __restrict__ xwh, const float* __restrict__ alsrc,
    const float* __restrict__ aldst, const int* __restrict__ row_ptr,
    const int* __restrict__ csr_src, const float* __restrict__ bias,
    float* __restrict__ out, int N) {
  constexpr int U = 8;
  int n = blockIdx.x * 4 + (threadIdx.x >> 6);
  if (n >= N) return;
  int lane = threadIdx.x & 63;
  int head = lane >> 3, g = lane & 7;
  float ad = aldst[(size_t)n * 8 + head];
  int start = row_ptr[n];
  int end = row_ptr[n + 1];
  int deg = end - start;
  int endm1 = end - 1;

  float m = -1e30f, s = 0.f;
  for (int j = g; j < deg; j += 8) {
    int sj = csr_src[start + j];
    float e = lrelu(alsrc[(size_t)sj * 8 + head] + ad);
    float mn = fmaxf(m, e);
    s = s * __expf(m - mn) + __expf(e - mn);
    m = mn;
  }
#pragma unroll
  for (int st = 1; st <= 4; st <<= 1) {
    float m2 = __shfl_xor(m, st);
    float s2 = __shfl_xor(s, st);
    float mn = fmaxf(m, m2);
    s = s * __expf(m - mn) + s2 * __expf(m2 - mn);
    m = mn;
  }
  float rr = 1.f / (s + 1e-16f);

  float a0 = 0.f, a1 = 0.f;
  int c[U];
#pragma unroll
  for (int i = 0; i < U; i++) c[i] = csr_src[min(start + i, endm1)];
  int j = 0;
  for (; j + U <= deg; j += U) {
    u32 v[U];
    float a[U];
#pragma unroll
    for (int i = 0; i < U; i++) v[i] = *(const u32*)(xwh + (size_t)c[i] * 128 + lane * 2);
#pragma unroll
    for (int i = 0; i < U; i++) a[i] = alsrc[(size_t)c[i] * 8 + head];
#pragma unroll
    for (int i = 0; i < U; i++) c[i] = csr_src[min(start + j + U + i, endm1)];
#pragma unroll
    for (int i = 0; i < U; i++) {
      float w = __expf(lrelu(a[i] + ad) - m) * rr;
      a0 = fmaf(w, bf2f(v[i] & 0xffffu), a0);
      a1 = fmaf(w, bf2f(v[i] >> 16), a1);
    }
  }
  for (int i = 0; j < deg; j++, i++) {
    u32 v = *(const u32*)(xwh + (size_t)c[i] * 128 + lane * 2);
    float w = __expf(lrelu(alsrc[(size_t)c[i] * 8 + head] + ad) - m) * rr;
    a0 = fmaf(w, bf2f(v & 0xffffu), a0);
    a1 = fmaf(w, bf2f(v >> 16), a1);
  }

#pragma unroll
  for (int st = 8; st <= 32; st <<= 1) {
    a0 += __shfl_xor(a0, st);
    a1 += __shfl_xor(a1, st);
  }
  int c0 = (2 * lane) & 15, c1 = (2 * lane + 1) & 15;
  float v0 = a0 * 0.125f + bias[c0];
  float v1 = a1 * 0.125f + bias[c1];
  float mx = fmaxf(v0, v1);
#pragma unroll
  for (int st = 1; st <= 4; st <<= 1) mx = fmaxf(mx, __shfl_xor(mx, st));
  float se = __expf(v0 - mx) + __expf(v1 - mx);
#pragma unroll
  for (int st = 1; st <= 4; st <<= 1) se += __shfl_xor(se, st);
  float lse = mx + logf(se);
  if (lane < 8) {
    float2 o = make_float2(v0 - lse, v1 - lse);
    *((float2*)(out + (size_t)n * 16) + lane) = o;
  }
}

// ---------------------------------------------------------------------------
extern "C" void kernel_launch(void* const* d_in, const int* in_sizes, int n_in,
                              void* d_out, int out_size, void* d_ws, size_t ws_size,
                              hipStream_t stream) {
  const float* x        = (const float*)d_in[0];
  const int*   ei       = (const int*)d_in[1];
  const float* bn_gamma = (const float*)d_in[2];
  const float* bn_beta  = (const float*)d_in[3];
  const float* W1       = (const float*)d_in[4];
  const float* a1s      = (const float*)d_in[5];
  const float* a1d      = (const float*)d_in[6];
  const float* b1       = (const float*)d_in[7];
  const float* p1       = (const float*)d_in[8];
  const float* W2       = (const float*)d_in[9];
  const float* a2s      = (const float*)d_in[10];
  const float* a2d      = (const float*)d_in[11];
  const float* b2       = (const float*)d_in[12];
  const float* p2       = (const float*)d_in[13];
  const float* W3       = (const float*)d_in[14];
  const float* a3s      = (const float*)d_in[15];
  const float* a3d      = (const float*)d_in[16];
  const float* b3       = (const float*)d_in[17];
  float* out = (float*)d_out;

  const int F  = in_sizes[2];       // 256
  const int N  = in_sizes[0] / F;   // 20000
  const int E  = in_sizes[1] / 2;   // 320000
  const int ET = E + N;
  const int MP = ((N + 127) / 128) * 128;  // MFMA row padding

  size_t off = 0;
  auto alloc = [&](size_t bytes) -> char* {
    char* r = (char*)d_ws + off;
    off += (bytes + 255) & ~(size_t)255;
    return r;
  };
  float* musum   = (float*)alloc(F * 4);
  float* sqsum   = (float*)alloc(F * 4);
  float* scale   = (float*)alloc(F * 4);
  float* shift   = (float*)alloc(F * 4);
  int*   row_ptr = (int*)alloc((size_t)(N + 1) * 4);
  int*   cursor  = (int*)alloc((size_t)N * 4);
  int*   csr_src = (int*)alloc((size_t)ET * 4);
  float* al_s    = (float*)alloc((size_t)N * 16 * 4);
  float* al_d    = (float*)alloc((size_t)N * 16 * 4);
  u16*   Wt1     = (u16*)alloc((size_t)1152 * 256 * 2);
  u16*   Wt2     = (u16*)alloc((size_t)96 * 1280 * 2);
  u16*   Wt3     = (u16*)alloc((size_t)160 * 64 * 2);
  u16*   x_in_h  = (u16*)alloc((size_t)MP * 256 * 2);
  u16*   xw1h    = (u16*)alloc((size_t)MP * 1024 * 2);
  u16*   h1      = (u16*)alloc((size_t)MP * 1024 * 2);
  u16*   xw2h    = (u16*)alloc((size_t)MP * 64 * 2);
  u16*   h2h     = (u16*)alloc((size_t)MP * 64 * 2);
  u16*   xw3h    = (u16*)alloc((size_t)MP * 128 * 2);

  // ---- BatchNorm ----
  hipMemsetAsync(musum, 0, (size_t)2 * F * 4, stream);
  bn_stats_kernel<<<256, 256, 0, stream>>>(x, musum, sqsum, N, F);
  bn_finalize_kernel<<<1, F, 0, stream>>>(musum, sqsum, bn_gamma, bn_beta, scale, shift, N);
  int totalXF = N * F;
  bn_apply_bf16_kernel<<<(totalXF + 255) / 256, 256, 0, stream>>>(x, scale, shift, x_in_h,
                                                                  totalXF, F - 1);

  // ---- CSR by dst ----
  hipMemsetAsync(cursor, 0, (size_t)N * 4, stream);
  csr_count_kernel<<<(ET + 255) / 256, 256, 0, stream>>>(ei, E, N, cursor);
  csr_scan_kernel<<<1, 1024, 0, stream>>>(cursor, row_ptr, cursor, N);
  csr_fill_kernel<<<(ET + 255) / 256, 256, 0, stream>>>(ei, E, N, cursor, csr_src);

  // ---- weight prep ----
  {
    int total = 1024 * 256 + 64 * 1280 + 128 * 64 + 96 * 256 + 32 * 1280 + 32 * 64;
    wt_build_all<<<(total + 255) / 256, 256, 0, stream>>>(W1, W2, W3, Wt1, Wt2, Wt3);
    int tot2 = 32 * 256 + 16 * 1280 + 16 * 64;
    alfold_build<<<(tot2 + 255) / 256, 256, 0, stream>>>(W1, a1s, a1d, W2, a2s, a2d, W3, a3s, a3d,
                                                         Wt1, Wt2, Wt3);
  }

  int nblk = (N + 3) / 4;

  // ---- Layer 1: [N,256]@[256,1024(+32al)] MFMA, H=16, C=64 ----
  {
    dim3 grid(MP / 128, 9);  // 9th tile covers al cols 1024..1151
    mfma_gemm_al<128, 128, 4, 4><<<grid, 256, 0, stream>>>(
        x_in_h, x_in_h, 256, 256, Wt1, xw1h, 1024, al_s, al_d, 32, N);
    gat_agg1_wave<<<(2 * N + 3) / 4, 256, 0, stream>>>(xw1h, al_s, al_d, row_ptr, csr_src, b1, p1,
                                                       h1, N);
  }

  // ---- Layer 2: concat([x_in,h1]) [N,1280]@[1280,64+16al] MFMA, H=8, C=8 ----
  {
    dim3 grid((N + 63) / 64, 1);
    mfma_gemm_al<64, 96, 2, 3><<<grid, 256, 0, stream>>>(
        x_in_h, h1, 256, 1280, Wt2, xw2h, 64, al_s, al_d, 16, N);
    gat_agg2_wave<<<nblk, 256, 0, stream>>>(xw2h, al_s, al_d, row_ptr, csr_src, b2, p2, h2h, N);
  }

  // ---- Layer 3: [N,64]@[64,128+16al] MFMA, H=8, C=16, mean + log_softmax ----
  {
    dim3 grid((N + 63) / 64, 1);
    mfma_gemm_al<64, 160, 2, 5><<<grid, 256, 0, stream>>>(
        h2h, h2h, 64, 64, Wt3, xw3h, 128, al_s, al_d, 16, N);
    gat_agg3_wave<<<nblk, 256, 0, stream>>>(xw3h, al_s, al_d, row_ptr, csr_src, b3, out, N);
  }
}